// Round 11
// baseline (96.826 us; speedup 1.0000x reference)
//
#include <hip/hip_runtime.h>
#include <hip/hip_bf16.h>
#include <math.h>

#define NBATCH 4
#define LTOK   4096
#define FD     64
#define KSPLIT 8
#define MBLK   16    // 32-k fragment blocks per flash block = 4096/KSPLIT/32

typedef __attribute__((ext_vector_type(8))) short short8v;   // 8 bf16 = 4 VGPR
typedef __attribute__((ext_vector_type(4))) float f32x4;
typedef __attribute__((ext_vector_type(16))) float f32x16;

static __device__ inline uint32_t packbf2(float a, float b) {
    float2 f; f.x = a; f.y = b;
    __hip_bfloat162 h = __float22bfloat162_rn(f);
    uint32_t u; __builtin_memcpy(&u, &h, 4);
    return u;
}
static __device__ inline ushort packbf1(float a) {
    __hip_bfloat16 h = __float2bfloat16(a);
    ushort u; __builtin_memcpy(&u, &h, 2);
    return u;
}
static __device__ inline float gelu_exact(float y) {
    return 0.5f * y * (1.0f + erff(y * 0.70710678118654752f));
}

// ---------------------------------------------------------------------------
// K1: GroupNorm partial sums. 256 blocks (64 chunks per batch), coalesced.
__global__ void gn_part_kernel(const float* __restrict__ x,
                               float* __restrict__ partS, float* __restrict__ partSS) {
    const int b = blockIdx.x >> 6, c = blockIdx.x & 63;
    const int t = threadIdx.x, l = t & 63, wv = t >> 6;
    const float4* xb = (const float4*)(x + (size_t)b * 262144) + (size_t)c * 1024;
    float s = 0.f, ss = 0.f;
#pragma unroll
    for (int k = 0; k < 4; k++) {
        float4 v = xb[t + 256 * k];
        s += (v.x + v.y) + (v.z + v.w);
        ss += (v.x * v.x + v.y * v.y) + (v.z * v.z + v.w * v.w);
    }
#pragma unroll
    for (int o = 0; o < 4; o++) {
        const int off = (int[]){1, 2, 16, 32}[o];
        s += __shfl_xor(s, off, 64);
        ss += __shfl_xor(ss, off, 64);
    }
    __shared__ float ls_s[4][4], ls_ss[4][4];
    if ((l & 51) == 0) { ls_s[wv][(l >> 2) & 3] = s; ls_ss[wv][(l >> 2) & 3] = ss; }
    __syncthreads();
    if (t < 4) {
        float S = 0.f, SS = 0.f;
#pragma unroll
        for (int w2 = 0; w2 < 4; w2++) { S += ls_s[w2][t]; SS += ls_ss[w2][t]; }
        partS[b * 256 + t * 64 + c] = S;
        partSS[b * 256 + t * 64 + c] = SS;
    }
}

// ---------------------------------------------------------------------------
// K2: combine partials + GN-apply + conv1 + channels-first reshape.
__global__ void gn_conv1_kernel(const float* __restrict__ x,
                                const float* __restrict__ partS, const float* __restrict__ partSS,
                                const float* __restrict__ gg, const float* __restrict__ gb,
                                const float* __restrict__ w, const float* __restrict__ bias,
                                float* __restrict__ out) {
    const int b = blockIdx.x >> 6, i = blockIdx.x & 63;
    const int t = threadIdx.x;
    __shared__ float xn[64][65];
    __shared__ float wsm[64][64];   // [c][o]
    __shared__ float sm[4], sr[4];
    {
        float sv = partS[b * 256 + t];     // g = t>>6, chunk = t&63
        float ssv = partSS[b * 256 + t];
        for (int o = 32; o; o >>= 1) { sv += __shfl_xor(sv, o, 64); ssv += __shfl_xor(ssv, o, 64); }
        if ((t & 63) == 0) {
            float mean = sv * (1.f / 65536.f);
            float var = ssv * (1.f / 65536.f) - mean * mean;
            sm[t >> 6] = mean;
            sr[t >> 6] = rsqrtf(var + 1e-5f);
        }
    }
    __syncthreads();
    {
        const int j = t >> 2, c0 = (t & 3) * 16, g = c0 >> 4;
        const float mean = sm[g], rstd = sr[g];
        const float* src = x + (((size_t)b * 64 + i) * 64 + j) * 64 + c0;
#pragma unroll
        for (int k = 0; k < 4; k++) {
            float4 v = *(const float4*)(src + 4 * k);
            xn[j][c0 + 4 * k + 0] = (v.x - mean) * rstd * gg[c0 + 4 * k + 0] + gb[c0 + 4 * k + 0];
            xn[j][c0 + 4 * k + 1] = (v.y - mean) * rstd * gg[c0 + 4 * k + 1] + gb[c0 + 4 * k + 1];
            xn[j][c0 + 4 * k + 2] = (v.z - mean) * rstd * gg[c0 + 4 * k + 2] + gb[c0 + 4 * k + 2];
            xn[j][c0 + 4 * k + 3] = (v.w - mean) * rstd * gg[c0 + 4 * k + 3] + gb[c0 + 4 * k + 3];
        }
        const int o = t >> 2, cc0 = (t & 3) * 16;
#pragma unroll
        for (int k = 0; k < 16; k++) wsm[cc0 + k][o] = w[o * 64 + cc0 + k];
    }
    __syncthreads();
    const int jj = t & 63, olo = (t >> 6) * 16;
    float acc[16];
#pragma unroll
    for (int oi = 0; oi < 16; oi++) acc[oi] = bias[olo + oi];
    for (int c = 0; c < 64; c++) {
        float xv = xn[jj][c];
#pragma unroll
        for (int oi = 0; oi < 16; oi++) acc[oi] += xv * wsm[c][olo + oi];
    }
#pragma unroll
    for (int oi = 0; oi < 16; oi++)
        out[((size_t)b * LTOK + (size_t)(olo + oi) * 64 + i) * 64 + jj] = acc[oi];
}

// ---------------------------------------------------------------------------
// K3: Q/K/V projection, one phase per block (grid 256 x 3). R8-verified.
__global__ void qkv_kernel(const float* __restrict__ in,
                           const float* __restrict__ qw, const float* __restrict__ qb,
                           const float* __restrict__ kw, const float* __restrict__ kb,
                           const float* __restrict__ vw, const float* __restrict__ vb,
                           ushort* __restrict__ Qo, ushort* __restrict__ KF, ushort* __restrict__ VF) {
    __shared__ float xt[64][68];
    __shared__ float wt[64][64];
    __shared__ ushort vtr[64 * 72];
    const int t = threadIdx.x;
    const int ph = blockIdx.y;
    const size_t tok0 = (size_t)blockIdx.x * 64;
    const int b = blockIdx.x >> 6;
    const int tokb0 = (blockIdx.x & 63) * 64;
    const int r = t >> 2, cq = t & 3, olo = cq * 16;
    const float* W = (ph == 0) ? qw : (ph == 1) ? kw : vw;
    const float* Bb = (ph == 0) ? qb : (ph == 1) ? kb : vb;
    {
        const float4* src = (const float4*)(in + tok0 * 64) + (size_t)t * 4;
        float4* dst = (float4*)&xt[r][olo];
#pragma unroll
        for (int k = 0; k < 4; k++) dst[k] = src[k];
        const float4* ws2 = (const float4*)W + (size_t)t * 4;
        float4* wd = (float4*)wt + (size_t)t * 4;
#pragma unroll
        for (int k = 0; k < 4; k++) wd[k] = ws2[k];
    }
    __syncthreads();
    float acc[16];
#pragma unroll
    for (int k = 0; k < 4; k++) {
        float4 bv = *(const float4*)(Bb + olo + 4 * k);
        acc[4 * k] = bv.x; acc[4 * k + 1] = bv.y; acc[4 * k + 2] = bv.z; acc[4 * k + 3] = bv.w;
    }
    for (int f = 0; f < 64; f++) {
        float xv = xt[r][f];
#pragma unroll
        for (int oi = 0; oi < 16; oi++) acc[oi] += xv * wt[f][olo + oi];
    }
    if (ph == 0) {
        const float sc = 0.180336880111f;   // 0.125 * log2(e)
        uint32_t u[8];
#pragma unroll
        for (int i = 0; i < 8; i++) u[i] = packbf2(acc[2 * i] * sc, acc[2 * i + 1] * sc);
        ushort* op = Qo + (tok0 + r) * 64 + olo;
        *(uint4*)op = make_uint4(u[0], u[1], u[2], u[3]);
        *(uint4*)(op + 8) = make_uint4(u[4], u[5], u[6], u[7]);
    } else if (ph == 1) {
        uint32_t u[8];
#pragma unroll
        for (int i = 0; i < 8; i++) u[i] = packbf2(acc[2 * i], acc[2 * i + 1]);
        const int tokb = tokb0 + r;
        const int m = tokb >> 5, tq = tokb & 31;
        const int hh = cq >> 1, f = cq & 1;
        const int bhh = b * 2 + hh;
        ushort* p0 = KF + ((size_t)(bhh * 128 + m) * 2 + f) * 512;
        *(uint4*)(p0 + tq * 8)        = make_uint4(u[0], u[1], u[2], u[3]);   // sig=0
        *(uint4*)(p0 + (32 + tq) * 8) = make_uint4(u[4], u[5], u[6], u[7]);   // sig=1
    } else {
#pragma unroll
        for (int oi = 0; oi < 16; oi++) vtr[(olo + oi) * 72 + r] = packbf1(acc[oi]);
        __syncthreads();
        const int o = t >> 2, ch = t & 3;
        const int lq2 = o & 31, hh = o >> 5, bhh = b * 2 + hh;
        const int m = (tokb0 >> 5) + (ch >> 1), f = ch & 1;
        uint4 a0 = *(const uint4*)&vtr[o * 72 + ch * 16];
        uint4 a1 = *(const uint4*)&vtr[o * 72 + ch * 16 + 8];
        ushort* p0 = VF + ((size_t)(bhh * 128 + m) * 2 + f) * 512;
        *(uint4*)(p0 + lq2 * 8)        = a0;   // sig=0
        *(uint4*)(p0 + (32 + lq2) * 8) = a1;   // sig=1
    }
}

// ---------------------------------------------------------------------------
// K4: MFMA flash — no LDS/barriers, fragment loads from L2. 32 q per wave.
// Grid (32, 8, 8) = 2048 blocks. Unchanged from R10.
__global__ __launch_bounds__(256, 5) void flash_mfma(const ushort* __restrict__ Q,
                                                     const ushort* __restrict__ KF,
                                                     const ushort* __restrict__ VF,
                                                     ushort* __restrict__ ZpAll,
                                                     float* __restrict__ Ls) {
    const int qt = blockIdx.x;            // 0..31 (128-q tiles)
    const int bh = blockIdx.y;            // 0..7
    const int ks = blockIdx.z;            // 0..7
    const int b = bh >> 1, h = bh & 1;
    const int t = threadIdx.x;
    const int w = t >> 6, l = t & 63, lq = l & 31, sig = l >> 5;

    const size_t base = (size_t)b * LTOK * 64 + h * 32;
    const int q0 = qt * 128 + w * 32;

    const ushort* qp = Q + base + (size_t)(q0 + lq) * 64 + 8 * sig;
    const short8v qf0 = *(const short8v*)(qp);
    const short8v qf1 = *(const short8v*)(qp + 16);

    const ushort* kfp = KF + ((size_t)(bh * 128 + ks * MBLK) * 2) * 512 + l * 8;
    const ushort* vfp = VF + ((size_t)(bh * 128 + ks * MBLK) * 2) * 512 + l * 8;

    f32x16 acc;
#pragma unroll
    for (int i = 0; i < 16; i++) acc[i] = 0.f;
    float lacc0 = 0.f, lacc1 = 0.f;

#pragma unroll 2
    for (int m = 0; m < MBLK; m++) {
        const short8v kf0 = *(const short8v*)kfp;
        const short8v kf1 = *(const short8v*)(kfp + 512);
        const short8v vf0 = *(const short8v*)vfp;
        const short8v vf1 = *(const short8v*)(vfp + 512);
        kfp += 1024; vfp += 1024;

        f32x16 st;
#pragma unroll
        for (int i = 0; i < 16; i++) st[i] = 0.f;
        st = __builtin_amdgcn_mfma_f32_32x32x16_bf16(kf0, qf0, st, 0, 0, 0);
        st = __builtin_amdgcn_mfma_f32_32x32x16_bf16(kf1, qf1, st, 0, 0, 0);

        uint32_t pk[8];
#pragma unroll
        for (int i = 0; i < 8; i++) {
            float p0 = __builtin_amdgcn_exp2f(st[2 * i]);
            float p1 = __builtin_amdgcn_exp2f(st[2 * i + 1]);
            if (i & 1) lacc1 += p0 + p1; else lacc0 += p0 + p1;
            pk[i] = packbf2(p0, p1);
        }
        uint32_t w0 = pk[0], w2 = pk[2], w1 = pk[1], w3 = pk[3];
        uint32_t x0 = pk[4], x2 = pk[6], x1 = pk[5], x3 = pk[7];
        asm volatile("v_permlane32_swap_b32 %0, %1" : "+v"(w0), "+v"(w2));
        asm volatile("v_permlane32_swap_b32 %0, %1" : "+v"(w1), "+v"(w3));
        asm volatile("v_permlane32_swap_b32 %0, %1" : "+v"(x0), "+v"(x2));
        asm volatile("v_permlane32_swap_b32 %0, %1" : "+v"(x1), "+v"(x3));
        uint4 A0 = make_uint4(w0, w1, w2, w3), A1 = make_uint4(x0, x1, x2, x3);
        short8v aP0, aP1;
        __builtin_memcpy(&aP0, &A0, 16);
        __builtin_memcpy(&aP1, &A1, 16);

        acc = __builtin_amdgcn_mfma_f32_32x32x16_bf16(aP0, vf0, acc, 0, 0, 0);
        acc = __builtin_amdgcn_mfma_f32_32x32x16_bf16(aP1, vf1, acc, 0, 0, 0);
    }

    ushort* Zo = ZpAll + (size_t)ks * (NBATCH * LTOK * FD);
#pragma unroll
    for (int r = 0; r < 16; r++) {
        const int qr = q0 + (r & 3) + 8 * (r >> 2) + 4 * sig;
        Zo[base + (size_t)qr * 64 + lq] = packbf1(acc[r]);
    }
    float lacc = lacc0 + lacc1;
    lacc += __shfl_xor(lacc, 32, 64);
    if (l < 32)
        Ls[ks * 32768 + bh * 4096 + q0 + lq] = lacc;
}

// ---------------------------------------------------------------------------
// K8: fused tail — 1024 blocks x 128 threads, 16 tokens per block (4 blk/CU).
__global__ __launch_bounds__(128) void tail_fused(
    const ushort* __restrict__ ZpAll,
    const float* __restrict__ Ls, const float* __restrict__ xs0,
    const float* __restrict__ slots,
    const float* __restrict__ ckw, const float* __restrict__ ckb,
    const float* __restrict__ cvw, const float* __restrict__ cvb,
    const float* __restrict__ ow, const float* __restrict__ ob,
    const float* __restrict__ g2, const float* __restrict__ b2,
    const float* __restrict__ qw, const float* __restrict__ qb,
    const float* __restrict__ cow, const float* __restrict__ cob,
    const float* __restrict__ g3, const float* __restrict__ b3,
    const float* __restrict__ fw, const float* __restrict__ fb,
    const float* __restrict__ g4, const float* __restrict__ b4,
    const float* __restrict__ cw, const float* __restrict__ cb,
    float* __restrict__ out)
{
    const int t = threadIdx.x;
    const size_t tok0 = (size_t)blockIdx.x * 16;
    const int b = blockIdx.x >> 8;
    const int r = t >> 3, c = t & 7, olo = c * 8;
    __shared__ float xt[16][68];
    __shared__ float wt[64][64];
    __shared__ float kcs[512], vcs[512], sls[512];

    float acc[8], res[8];

    auto stage_w = [&](const float* W) {
#pragma unroll
        for (int k = 0; k < 8; k++)
            ((float4*)wt)[8 * t + k] = ((const float4*)W)[8 * t + k];
    };
    auto stage_x_res = [&]() {
        float4* xd = (float4*)&xt[r][olo];
        xd[0] = make_float4(res[0], res[1], res[2], res[3]);
        xd[1] = make_float4(res[4], res[5], res[6], res[7]);
    };
    auto load8 = [&](float* dst, const float* p) {
        float4 u0 = *(const float4*)(p + olo);
        float4 u1 = *(const float4*)(p + olo + 4);
        dst[0] = u0.x; dst[1] = u0.y; dst[2] = u0.z; dst[3] = u0.w;
        dst[4] = u1.x; dst[5] = u1.y; dst[6] = u1.z; dst[7] = u1.w;
    };
    auto mm = [&](const float* bias) {
        load8(acc, bias);
        for (int f = 0; f < 64; f++) {
            float xv = xt[r][f];
#pragma unroll
            for (int oi = 0; oi < 8; oi++) acc[oi] += xv * wt[f][olo + oi];
        }
    };
    auto ln = [&](const float* gv, const float* bv, bool dogelu) {
        float s1 = 0.f, s2 = 0.f;
#pragma unroll
        for (int oi = 0; oi < 8; oi++) { s1 += acc[oi]; s2 += acc[oi] * acc[oi]; }
#pragma unroll
        for (int o = 1; o <= 4; o <<= 1) {
            s1 += __shfl_xor(s1, o, 64);
            s2 += __shfl_xor(s2, o, 64);
        }
        float mean = s1 * (1.f / 64.f);
        float var = s2 * (1.f / 64.f) - mean * mean;
        float rstd = rsqrtf(var + 1e-5f);
        float gl[8], bl[8];
        load8(gl, gv); load8(bl, bv);
#pragma unroll
        for (int oi = 0; oi < 8; oi++) {
            float y = (acc[oi] - mean) * rstd * gl[oi] + bl[oi] + res[oi];
            res[oi] = dogelu ? gelu_exact(y) : y;
        }
    };

    // ---- phase 1: combine 8 bf16 flash partials, t0 = Z@ow+ob ; res = xs1
    {
        ((float4*)sls)[t] = ((const float4*)(slots + (size_t)b * 512))[t];
        float zs[8];
#pragma unroll
        for (int j = 0; j < 8; j++) zs[j] = 0.f;
#pragma unroll
        for (int kb = 0; kb < KSPLIT; kb++) {
            const uint4 u = *(const uint4*)(ZpAll + (size_t)kb * (NBATCH * LTOK * FD)
                                            + tok0 * 64 + (size_t)t * 8);
            const uint32_t arr[4] = {u.x, u.y, u.z, u.w};
#pragma unroll
            for (int j = 0; j < 4; j++) {
                zs[2 * j]     += __uint_as_float(arr[j] << 16);
                zs[2 * j + 1] += __uint_as_float(arr[j] & 0xffff0000u);
            }
        }
        const int hh = olo >> 5;
        const int bh_ = b * 2 + hh;
        const int tokb = (blockIdx.x & 255) * 16 + r;
        float lt = 0.f;
#pragma unroll
        for (int kb = 0; kb < KSPLIT; kb++) lt += Ls[kb * 32768 + bh_ * 4096 + tokb];
        const float inv = 1.0f / lt;
        float4* xd = (float4*)&xt[r][olo];
        xd[0] = make_float4(zs[0] * inv, zs[1] * inv, zs[2] * inv, zs[3] * inv);
        xd[1] = make_float4(zs[4] * inv, zs[5] * inv, zs[6] * inv, zs[7] * inv);
        stage_w(ow);
        float4 r0 = *(const float4*)(xs0 + (tok0 + r) * 64 + olo);
        float4 r1 = *(const float4*)(xs0 + (tok0 + r) * 64 + olo + 4);
        res[0] = r0.x; res[1] = r0.y; res[2] = r0.z; res[3] = r0.w;
        res[4] = r1.x; res[5] = r1.y; res[6] = r1.z; res[7] = r1.w;
    }
    __syncthreads();
    // ---- cross-attn K/V from slots (redundant per block, cheap)
    for (int jo = t; jo < 512; jo += 128) {
        const int j = jo >> 6, o = jo & 63;
        float ak = ckb[o], av = cvb[o];
#pragma unroll 8
        for (int c2 = 0; c2 < 64; c2++) {
            float sv = sls[j * 64 + c2];
            ak += sv * ckw[c2 * 64 + o];
            av += sv * cvw[c2 * 64 + o];
        }
        kcs[jo] = ak; vcs[jo] = av;
    }
    mm(ob);
    ln(g2, b2, true);

    // ---- phase 2: qca = xs1@qw+qb ; acc = cross-attn(zca)
    __syncthreads();
    stage_x_res();
    stage_w(qw);
    __syncthreads();
    mm(qb);
    {
        float p[8];
        float mx = -3.0e38f;
#pragma unroll
        for (int j = 0; j < 8; j++) {
            float d = 0.f;
#pragma unroll
            for (int i2 = 0; i2 < 8; i2++) d += acc[i2] * kcs[j * 64 + olo + i2];
            d += __shfl_xor(d, 1, 64);
            d += __shfl_xor(d, 2, 64);
            d *= 0.125f;
            p[j] = d;
            mx = fmaxf(mx, d);
        }
        float es = 0.f;
#pragma unroll
        for (int j = 0; j < 8; j++) { p[j] = __expf(p[j] - mx); es += p[j]; }
        float inv = 1.f / es;
#pragma unroll
        for (int oi = 0; oi < 8; oi++) {
            float z = 0.f;
#pragma unroll
            for (int j = 0; j < 8; j++) z += p[j] * vcs[j * 64 + olo + oi];
            acc[oi] = z * inv;
        }
    }

    // ---- phase 3: t1 = zca@cow+cob ; res = xs2 = LN3(t1)+xs1
    __syncthreads();
    {
        float4* xd = (float4*)&xt[r][olo];
        xd[0] = make_float4(acc[0], acc[1], acc[2], acc[3]);
        xd[1] = make_float4(acc[4], acc[5], acc[6], acc[7]);
    }
    stage_w(cow);
    __syncthreads();
    mm(cob);
    ln(g3, b3, false);

    // ---- phase 4: t2 = xs2@fw+fb ; res = xs3 = LN4(t2)+xs2
    __syncthreads();
    stage_x_res();
    stage_w(fw);
    __syncthreads();
    mm(fb);
    ln(g4, b4, false);

    // ---- phase 5: out = xs3 @ conv2^T + cb
    __syncthreads();
    stage_x_res();
    {
        const int o5 = t >> 1, c5 = (t & 1) * 32;
#pragma unroll
        for (int k = 0; k < 32; k++) wt[c5 + k][o5] = cw[o5 * 64 + c5 + k];
    }
    __syncthreads();
    mm(cb);
    float* op = out + (tok0 + r) * 64 + olo;
    *(float4*)op = make_float4(acc[0], acc[1], acc[2], acc[3]);
    *(float4*)(op + 4) = make_float4(acc[4], acc[5], acc[6], acc[7]);
}

// ---------------------------------------------------------------------------
extern "C" void kernel_launch(void* const* d_in, const int* in_sizes, int n_in,
                              void* d_out, int out_size, void* d_ws, size_t ws_size,
                              hipStream_t stream) {
    const float* x       = (const float*)d_in[0];
    const float* slots   = (const float*)d_in[1];
    const float* conv1_w = (const float*)d_in[2];
    const float* conv1_b = (const float*)d_in[3];
    const float* conv2_w = (const float*)d_in[4];
    const float* conv2_b = (const float*)d_in[5];
    const float* gn_g    = (const float*)d_in[6];
    const float* gn_b    = (const float*)d_in[7];
    const float* ln2_g   = (const float*)d_in[8];
    const float* ln2_b   = (const float*)d_in[9];
    const float* ln3_g   = (const float*)d_in[10];
    const float* ln3_b   = (const float*)d_in[11];
    const float* ln4_g   = (const float*)d_in[12];
    const float* ln4_b   = (const float*)d_in[13];
    const float* sa_qw   = (const float*)d_in[14];
    const float* sa_qb   = (const float*)d_in[15];
    const float* sa_kw   = (const float*)d_in[16];
    const float* sa_kb   = (const float*)d_in[17];
    const float* sa_vw   = (const float*)d_in[18];
    const float* sa_vb   = (const float*)d_in[19];
    const float* sa_ow   = (const float*)d_in[20];
    const float* sa_ob   = (const float*)d_in[21];
    const float* ca_qw   = (const float*)d_in[22];
    const float* ca_qb   = (const float*)d_in[23];
    const float* ca_kw   = (const float*)d_in[24];
    const float* ca_kb   = (const float*)d_in[25];
    const float* ca_vw   = (const float*)d_in[26];
    const float* ca_vb   = (const float*)d_in[27];
    const float* ca_ow   = (const float*)d_in[28];
    const float* ca_ob   = (const float*)d_in[29];
    const float* ff1_w   = (const float*)d_in[30];
    const float* ff1_b   = (const float*)d_in[31];

    float* ws = (float*)d_ws;
    const size_t NBUF = (size_t)NBATCH * LTOK * FD;   // 1,048,576 elements
    float* partS  = ws;                    // 1024
    float* partSS = ws + 1024;             // 1024
    float* A      = ws + 4096;             // xs0, 4 MB
    ushort* KF    = (ushort*)(A + NBUF);   // 2 MB (fragment layout)
    ushort* VF    = KF + NBUF;             // 2 MB (fragment layout)
    ushort* Qb    = VF + NBUF;             // 2 MB
    ushort* ZpAll = Qb + NBUF;             // 8 x 2 MB bf16 partials
    float* Ls     = (float*)(ZpAll + (size_t)KSPLIT * NBUF);  // 8 x 32768 floats

    gn_part_kernel<<<256, 256, 0, stream>>>(x, partS, partSS);
    gn_conv1_kernel<<<256, 256, 0, stream>>>(x, partS, partSS, gn_g, gn_b, conv1_w, conv1_b, A);
    qkv_kernel<<<dim3(256, 3), 256, 0, stream>>>(A, sa_qw, sa_qb, sa_kw, sa_kb, sa_vw, sa_vb, Qb, KF, VF);
    flash_mfma<<<dim3(32, 8, KSPLIT), 256, 0, stream>>>(Qb, KF, VF, ZpAll, Ls);
    tail_fused<<<1024, 128, 0, stream>>>(ZpAll, Ls, A, slots,
                                         ca_kw, ca_kb, ca_vw, ca_vb,
                                         sa_ow, sa_ob, ln2_g, ln2_b,
                                         ca_qw, ca_qb, ca_ow, ca_ob, ln3_g, ln3_b,
                                         ff1_w, ff1_b, ln4_g, ln4_b,
                                         conv2_w, conv2_b, (float*)d_out);
}

// Round 12
// 88.706 us; speedup vs baseline: 1.0915x; 1.0915x over previous
//
#include <hip/hip_runtime.h>
#include <hip/hip_bf16.h>
#include <math.h>

#define NBATCH 4
#define LTOK   4096
#define FD     64
#define KSPLIT 4
#define MBLK   32    // 32-k fragment blocks per flash block = 4096/KSPLIT/32

typedef __attribute__((ext_vector_type(8))) short short8v;   // 8 bf16 = 4 VGPR
typedef __attribute__((ext_vector_type(4))) float f32x4;
typedef __attribute__((ext_vector_type(16))) float f32x16;

static __device__ inline uint32_t packbf2(float a, float b) {
    float2 f; f.x = a; f.y = b;
    __hip_bfloat162 h = __float22bfloat162_rn(f);
    uint32_t u; __builtin_memcpy(&u, &h, 4);
    return u;
}
static __device__ inline ushort packbf1(float a) {
    __hip_bfloat16 h = __float2bfloat16(a);
    ushort u; __builtin_memcpy(&u, &h, 2);
    return u;
}
static __device__ inline float gelu_exact(float y) {
    return 0.5f * y * (1.0f + erff(y * 0.70710678118654752f));
}

// ---------------------------------------------------------------------------
// K1: GroupNorm partial sums. 256 blocks (64 chunks per batch), coalesced.
__global__ void gn_part_kernel(const float* __restrict__ x,
                               float* __restrict__ partS, float* __restrict__ partSS) {
    const int b = blockIdx.x >> 6, c = blockIdx.x & 63;
    const int t = threadIdx.x, l = t & 63, wv = t >> 6;
    const float4* xb = (const float4*)(x + (size_t)b * 262144) + (size_t)c * 1024;
    float s = 0.f, ss = 0.f;
#pragma unroll
    for (int k = 0; k < 4; k++) {
        float4 v = xb[t + 256 * k];
        s += (v.x + v.y) + (v.z + v.w);
        ss += (v.x * v.x + v.y * v.y) + (v.z * v.z + v.w * v.w);
    }
#pragma unroll
    for (int o = 0; o < 4; o++) {
        const int off = (int[]){1, 2, 16, 32}[o];
        s += __shfl_xor(s, off, 64);
        ss += __shfl_xor(ss, off, 64);
    }
    __shared__ float ls_s[4][4], ls_ss[4][4];
    if ((l & 51) == 0) { ls_s[wv][(l >> 2) & 3] = s; ls_ss[wv][(l >> 2) & 3] = ss; }
    __syncthreads();
    if (t < 4) {
        float S = 0.f, SS = 0.f;
#pragma unroll
        for (int w2 = 0; w2 < 4; w2++) { S += ls_s[w2][t]; SS += ls_ss[w2][t]; }
        partS[b * 256 + t * 64 + c] = S;
        partSS[b * 256 + t * 64 + c] = SS;
    }
}

// ---------------------------------------------------------------------------
// K2: combine partials + GN-apply + conv1 + channels-first reshape.
__global__ void gn_conv1_kernel(const float* __restrict__ x,
                                const float* __restrict__ partS, const float* __restrict__ partSS,
                                const float* __restrict__ gg, const float* __restrict__ gb,
                                const float* __restrict__ w, const float* __restrict__ bias,
                                float* __restrict__ out) {
    const int b = blockIdx.x >> 6, i = blockIdx.x & 63;
    const int t = threadIdx.x;
    __shared__ float xn[64][65];
    __shared__ float wsm[64][64];   // [c][o]
    __shared__ float sm[4], sr[4];
    {
        float sv = partS[b * 256 + t];     // g = t>>6, chunk = t&63
        float ssv = partSS[b * 256 + t];
        for (int o = 32; o; o >>= 1) { sv += __shfl_xor(sv, o, 64); ssv += __shfl_xor(ssv, o, 64); }
        if ((t & 63) == 0) {
            float mean = sv * (1.f / 65536.f);
            float var = ssv * (1.f / 65536.f) - mean * mean;
            sm[t >> 6] = mean;
            sr[t >> 6] = rsqrtf(var + 1e-5f);
        }
    }
    __syncthreads();
    {
        const int j = t >> 2, c0 = (t & 3) * 16, g = c0 >> 4;
        const float mean = sm[g], rstd = sr[g];
        const float* src = x + (((size_t)b * 64 + i) * 64 + j) * 64 + c0;
#pragma unroll
        for (int k = 0; k < 4; k++) {
            float4 v = *(const float4*)(src + 4 * k);
            xn[j][c0 + 4 * k + 0] = (v.x - mean) * rstd * gg[c0 + 4 * k + 0] + gb[c0 + 4 * k + 0];
            xn[j][c0 + 4 * k + 1] = (v.y - mean) * rstd * gg[c0 + 4 * k + 1] + gb[c0 + 4 * k + 1];
            xn[j][c0 + 4 * k + 2] = (v.z - mean) * rstd * gg[c0 + 4 * k + 2] + gb[c0 + 4 * k + 2];
            xn[j][c0 + 4 * k + 3] = (v.w - mean) * rstd * gg[c0 + 4 * k + 3] + gb[c0 + 4 * k + 3];
        }
        const int o = t >> 2, cc0 = (t & 3) * 16;
#pragma unroll
        for (int k = 0; k < 16; k++) wsm[cc0 + k][o] = w[o * 64 + cc0 + k];
    }
    __syncthreads();
    const int jj = t & 63, olo = (t >> 6) * 16;
    float acc[16];
#pragma unroll
    for (int oi = 0; oi < 16; oi++) acc[oi] = bias[olo + oi];
    for (int c = 0; c < 64; c++) {
        float xv = xn[jj][c];
#pragma unroll
        for (int oi = 0; oi < 16; oi++) acc[oi] += xv * wsm[c][olo + oi];
    }
#pragma unroll
    for (int oi = 0; oi < 16; oi++)
        out[((size_t)b * LTOK + (size_t)(olo + oi) * 64 + i) * 64 + jj] = acc[oi];
}

// ---------------------------------------------------------------------------
// K3: Q/K/V projection, one phase per block (grid 256 x 3). R8-verified.
__global__ void qkv_kernel(const float* __restrict__ in,
                           const float* __restrict__ qw, const float* __restrict__ qb,
                           const float* __restrict__ kw, const float* __restrict__ kb,
                           const float* __restrict__ vw, const float* __restrict__ vb,
                           ushort* __restrict__ Qo, ushort* __restrict__ KF, ushort* __restrict__ VF) {
    __shared__ float xt[64][68];
    __shared__ float wt[64][64];
    __shared__ ushort vtr[64 * 72];
    const int t = threadIdx.x;
    const int ph = blockIdx.y;
    const size_t tok0 = (size_t)blockIdx.x * 64;
    const int b = blockIdx.x >> 6;
    const int tokb0 = (blockIdx.x & 63) * 64;
    const int r = t >> 2, cq = t & 3, olo = cq * 16;
    const float* W = (ph == 0) ? qw : (ph == 1) ? kw : vw;
    const float* Bb = (ph == 0) ? qb : (ph == 1) ? kb : vb;
    {
        const float4* src = (const float4*)(in + tok0 * 64) + (size_t)t * 4;
        float4* dst = (float4*)&xt[r][olo];
#pragma unroll
        for (int k = 0; k < 4; k++) dst[k] = src[k];
        const float4* ws2 = (const float4*)W + (size_t)t * 4;
        float4* wd = (float4*)wt + (size_t)t * 4;
#pragma unroll
        for (int k = 0; k < 4; k++) wd[k] = ws2[k];
    }
    __syncthreads();
    float acc[16];
#pragma unroll
    for (int k = 0; k < 4; k++) {
        float4 bv = *(const float4*)(Bb + olo + 4 * k);
        acc[4 * k] = bv.x; acc[4 * k + 1] = bv.y; acc[4 * k + 2] = bv.z; acc[4 * k + 3] = bv.w;
    }
    for (int f = 0; f < 64; f++) {
        float xv = xt[r][f];
#pragma unroll
        for (int oi = 0; oi < 16; oi++) acc[oi] += xv * wt[f][olo + oi];
    }
    if (ph == 0) {
        const float sc = 0.180336880111f;   // 0.125 * log2(e)
        uint32_t u[8];
#pragma unroll
        for (int i = 0; i < 8; i++) u[i] = packbf2(acc[2 * i] * sc, acc[2 * i + 1] * sc);
        ushort* op = Qo + (tok0 + r) * 64 + olo;
        *(uint4*)op = make_uint4(u[0], u[1], u[2], u[3]);
        *(uint4*)(op + 8) = make_uint4(u[4], u[5], u[6], u[7]);
    } else if (ph == 1) {
        uint32_t u[8];
#pragma unroll
        for (int i = 0; i < 8; i++) u[i] = packbf2(acc[2 * i], acc[2 * i + 1]);
        const int tokb = tokb0 + r;
        const int m = tokb >> 5, tq = tokb & 31;
        const int hh = cq >> 1, f = cq & 1;
        const int bhh = b * 2 + hh;
        ushort* p0 = KF + ((size_t)(bhh * 128 + m) * 2 + f) * 512;
        *(uint4*)(p0 + tq * 8)        = make_uint4(u[0], u[1], u[2], u[3]);   // sig=0
        *(uint4*)(p0 + (32 + tq) * 8) = make_uint4(u[4], u[5], u[6], u[7]);   // sig=1
    } else {
#pragma unroll
        for (int oi = 0; oi < 16; oi++) vtr[(olo + oi) * 72 + r] = packbf1(acc[oi]);
        __syncthreads();
        const int o = t >> 2, ch = t & 3;
        const int lq2 = o & 31, hh = o >> 5, bhh = b * 2 + hh;
        const int m = (tokb0 >> 5) + (ch >> 1), f = ch & 1;
        uint4 a0 = *(const uint4*)&vtr[o * 72 + ch * 16];
        uint4 a1 = *(const uint4*)&vtr[o * 72 + ch * 16 + 8];
        ushort* p0 = VF + ((size_t)(bhh * 128 + m) * 2 + f) * 512;
        *(uint4*)(p0 + lq2 * 8)        = a0;   // sig=0
        *(uint4*)(p0 + (32 + lq2) * 8) = a1;   // sig=1
    }
}

// ---------------------------------------------------------------------------
// K4: MFMA flash — no LDS/barriers, fragment loads from L2. 32 q per wave.
// KSPLIT=4 (grid 32x8x4 = 1024 blocks), setprio around MFMA clusters.
__global__ __launch_bounds__(256, 5) void flash_mfma(const ushort* __restrict__ Q,
                                                     const ushort* __restrict__ KF,
                                                     const ushort* __restrict__ VF,
                                                     ushort* __restrict__ ZpAll,
                                                     float* __restrict__ Ls) {
    const int qt = blockIdx.x;            // 0..31 (128-q tiles)
    const int bh = blockIdx.y;            // 0..7
    const int ks = blockIdx.z;            // 0..3
    const int b = bh >> 1, h = bh & 1;
    const int t = threadIdx.x;
    const int w = t >> 6, l = t & 63, lq = l & 31, sig = l >> 5;

    const size_t base = (size_t)b * LTOK * 64 + h * 32;
    const int q0 = qt * 128 + w * 32;

    const ushort* qp = Q + base + (size_t)(q0 + lq) * 64 + 8 * sig;
    const short8v qf0 = *(const short8v*)(qp);
    const short8v qf1 = *(const short8v*)(qp + 16);

    const ushort* kfp = KF + ((size_t)(bh * 128 + ks * MBLK) * 2) * 512 + l * 8;
    const ushort* vfp = VF + ((size_t)(bh * 128 + ks * MBLK) * 2) * 512 + l * 8;

    f32x16 acc;
#pragma unroll
    for (int i = 0; i < 16; i++) acc[i] = 0.f;
    float lacc0 = 0.f, lacc1 = 0.f;

#pragma unroll 2
    for (int m = 0; m < MBLK; m++) {
        const short8v kf0 = *(const short8v*)kfp;
        const short8v kf1 = *(const short8v*)(kfp + 512);
        const short8v vf0 = *(const short8v*)vfp;
        const short8v vf1 = *(const short8v*)(vfp + 512);
        kfp += 1024; vfp += 1024;

        f32x16 st;
#pragma unroll
        for (int i = 0; i < 16; i++) st[i] = 0.f;
        __builtin_amdgcn_s_setprio(1);
        st = __builtin_amdgcn_mfma_f32_32x32x16_bf16(kf0, qf0, st, 0, 0, 0);
        st = __builtin_amdgcn_mfma_f32_32x32x16_bf16(kf1, qf1, st, 0, 0, 0);
        __builtin_amdgcn_s_setprio(0);

        uint32_t pk[8];
#pragma unroll
        for (int i = 0; i < 8; i++) {
            float p0 = __builtin_amdgcn_exp2f(st[2 * i]);
            float p1 = __builtin_amdgcn_exp2f(st[2 * i + 1]);
            if (i & 1) lacc1 += p0 + p1; else lacc0 += p0 + p1;
            pk[i] = packbf2(p0, p1);
        }
        uint32_t w0 = pk[0], w2 = pk[2], w1 = pk[1], w3 = pk[3];
        uint32_t x0 = pk[4], x2 = pk[6], x1 = pk[5], x3 = pk[7];
        asm volatile("v_permlane32_swap_b32 %0, %1" : "+v"(w0), "+v"(w2));
        asm volatile("v_permlane32_swap_b32 %0, %1" : "+v"(w1), "+v"(w3));
        asm volatile("v_permlane32_swap_b32 %0, %1" : "+v"(x0), "+v"(x2));
        asm volatile("v_permlane32_swap_b32 %0, %1" : "+v"(x1), "+v"(x3));
        uint4 A0 = make_uint4(w0, w1, w2, w3), A1 = make_uint4(x0, x1, x2, x3);
        short8v aP0, aP1;
        __builtin_memcpy(&aP0, &A0, 16);
        __builtin_memcpy(&aP1, &A1, 16);

        __builtin_amdgcn_s_setprio(1);
        acc = __builtin_amdgcn_mfma_f32_32x32x16_bf16(aP0, vf0, acc, 0, 0, 0);
        acc = __builtin_amdgcn_mfma_f32_32x32x16_bf16(aP1, vf1, acc, 0, 0, 0);
        __builtin_amdgcn_s_setprio(0);
    }

    ushort* Zo = ZpAll + (size_t)ks * (NBATCH * LTOK * FD);
#pragma unroll
    for (int r = 0; r < 16; r++) {
        const int qr = q0 + (r & 3) + 8 * (r >> 2) + 4 * sig;
        Zo[base + (size_t)qr * 64 + lq] = packbf1(acc[r]);
    }
    float lacc = lacc0 + lacc1;
    lacc += __shfl_xor(lacc, 32, 64);
    if (l < 32)
        Ls[ks * 32768 + bh * 4096 + q0 + lq] = lacc;
}

// ---------------------------------------------------------------------------
// K8: fused tail — Z-combine(4 bf16) + ow+LN2+GELU, ca_kv, ca_q, cross-attn,
// ca_ow+LN3, ff1+LN4, conv2. 512 blocks x 256 threads (R10-verified).
__global__ __launch_bounds__(256) void tail_fused(
    const ushort* __restrict__ ZpAll,
    const float* __restrict__ Ls, const float* __restrict__ xs0,
    const float* __restrict__ slots,
    const float* __restrict__ ckw, const float* __restrict__ ckb,
    const float* __restrict__ cvw, const float* __restrict__ cvb,
    const float* __restrict__ ow, const float* __restrict__ ob,
    const float* __restrict__ g2, const float* __restrict__ b2,
    const float* __restrict__ qw, const float* __restrict__ qb,
    const float* __restrict__ cow, const float* __restrict__ cob,
    const float* __restrict__ g3, const float* __restrict__ b3,
    const float* __restrict__ fw, const float* __restrict__ fb,
    const float* __restrict__ g4, const float* __restrict__ b4,
    const float* __restrict__ cw, const float* __restrict__ cb,
    float* __restrict__ out)
{
    const int t = threadIdx.x;
    const size_t tok0 = (size_t)blockIdx.x * 32;
    const int b = blockIdx.x >> 7;
    const int r = t >> 3, c = t & 7, olo = c * 8;
    __shared__ float xt[32][68];
    __shared__ float wt[64][64];
    __shared__ float kcs[512], vcs[512], sls[512];

    float acc[8], res[8];

    auto stage_w = [&](const float* W) {
#pragma unroll
        for (int k = 0; k < 4; k++)
            ((float4*)wt)[4 * t + k] = ((const float4*)W)[4 * t + k];
    };
    auto stage_x_res = [&]() {
        float4* xd = (float4*)&xt[r][olo];
        xd[0] = make_float4(res[0], res[1], res[2], res[3]);
        xd[1] = make_float4(res[4], res[5], res[6], res[7]);
    };
    auto load8 = [&](float* dst, const float* p) {
        float4 u0 = *(const float4*)(p + olo);
        float4 u1 = *(const float4*)(p + olo + 4);
        dst[0] = u0.x; dst[1] = u0.y; dst[2] = u0.z; dst[3] = u0.w;
        dst[4] = u1.x; dst[5] = u1.y; dst[6] = u1.z; dst[7] = u1.w;
    };
    auto mm = [&](const float* bias) {
        load8(acc, bias);
        for (int f = 0; f < 64; f++) {
            float xv = xt[r][f];
#pragma unroll
            for (int oi = 0; oi < 8; oi++) acc[oi] += xv * wt[f][olo + oi];
        }
    };
    auto ln = [&](const float* gv, const float* bv, bool dogelu) {
        float s1 = 0.f, s2 = 0.f;
#pragma unroll
        for (int oi = 0; oi < 8; oi++) { s1 += acc[oi]; s2 += acc[oi] * acc[oi]; }
#pragma unroll
        for (int o = 1; o <= 4; o <<= 1) {
            s1 += __shfl_xor(s1, o, 64);
            s2 += __shfl_xor(s2, o, 64);
        }
        float mean = s1 * (1.f / 64.f);
        float var = s2 * (1.f / 64.f) - mean * mean;
        float rstd = rsqrtf(var + 1e-5f);
        float gl[8], bl[8];
        load8(gl, gv); load8(bl, bv);
#pragma unroll
        for (int oi = 0; oi < 8; oi++) {
            float y = (acc[oi] - mean) * rstd * gl[oi] + bl[oi] + res[oi];
            res[oi] = dogelu ? gelu_exact(y) : y;
        }
    };

    // ---- phase 1: combine 4 bf16 flash partials, t0 = Z@ow+ob ; res = xs1
    {
        if (t < 128) ((float4*)sls)[t] = ((const float4*)(slots + (size_t)b * 512))[t];
        float zs[8];
#pragma unroll
        for (int j = 0; j < 8; j++) zs[j] = 0.f;
#pragma unroll
        for (int kb = 0; kb < KSPLIT; kb++) {
            const uint4 u = *(const uint4*)(ZpAll + (size_t)kb * (NBATCH * LTOK * FD)
                                            + tok0 * 64 + (size_t)t * 8);
            const uint32_t arr[4] = {u.x, u.y, u.z, u.w};
#pragma unroll
            for (int j = 0; j < 4; j++) {
                zs[2 * j]     += __uint_as_float(arr[j] << 16);
                zs[2 * j + 1] += __uint_as_float(arr[j] & 0xffff0000u);
            }
        }
        const int hh = olo >> 5;
        const int bh_ = b * 2 + hh;
        const int tokb = (blockIdx.x & 127) * 32 + r;
        float lt = 0.f;
#pragma unroll
        for (int kb = 0; kb < KSPLIT; kb++) lt += Ls[kb * 32768 + bh_ * 4096 + tokb];
        const float inv = 1.0f / lt;
        float4* xd = (float4*)&xt[r][olo];
        xd[0] = make_float4(zs[0] * inv, zs[1] * inv, zs[2] * inv, zs[3] * inv);
        xd[1] = make_float4(zs[4] * inv, zs[5] * inv, zs[6] * inv, zs[7] * inv);
        stage_w(ow);
        float4 r0 = *(const float4*)(xs0 + (tok0 + r) * 64 + olo);
        float4 r1 = *(const float4*)(xs0 + (tok0 + r) * 64 + olo + 4);
        res[0] = r0.x; res[1] = r0.y; res[2] = r0.z; res[3] = r0.w;
        res[4] = r1.x; res[5] = r1.y; res[6] = r1.z; res[7] = r1.w;
    }
    __syncthreads();
    // ---- cross-attn K/V from slots (redundant per block, cheap)
    for (int jo = t; jo < 512; jo += 256) {
        const int j = jo >> 6, o = jo & 63;
        float ak = ckb[o], av = cvb[o];
#pragma unroll 8
        for (int c2 = 0; c2 < 64; c2++) {
            float sv = sls[j * 64 + c2];
            ak += sv * ckw[c2 * 64 + o];
            av += sv * cvw[c2 * 64 + o];
        }
        kcs[jo] = ak; vcs[jo] = av;
    }
    mm(ob);
    ln(g2, b2, true);

    // ---- phase 2: qca = xs1@qw+qb ; acc = cross-attn(zca)
    __syncthreads();
    stage_x_res();
    stage_w(qw);
    __syncthreads();
    mm(qb);
    {
        float p[8];
        float mx = -3.0e38f;
#pragma unroll
        for (int j = 0; j < 8; j++) {
            float d = 0.f;
#pragma unroll
            for (int i2 = 0; i2 < 8; i2++) d += acc[i2] * kcs[j * 64 + olo + i2];
            d += __shfl_xor(d, 1, 64);
            d += __shfl_xor(d, 2, 64);
            d *= 0.125f;
            p[j] = d;
            mx = fmaxf(mx, d);
        }
        float es = 0.f;
#pragma unroll
        for (int j = 0; j < 8; j++) { p[j] = __expf(p[j] - mx); es += p[j]; }
        float inv = 1.f / es;
#pragma unroll
        for (int oi = 0; oi < 8; oi++) {
            float z = 0.f;
#pragma unroll
            for (int j = 0; j < 8; j++) z += p[j] * vcs[j * 64 + olo + oi];
            acc[oi] = z * inv;
        }
    }

    // ---- phase 3: t1 = zca@cow+cob ; res = xs2 = LN3(t1)+xs1
    __syncthreads();
    {
        float4* xd = (float4*)&xt[r][olo];
        xd[0] = make_float4(acc[0], acc[1], acc[2], acc[3]);
        xd[1] = make_float4(acc[4], acc[5], acc[6], acc[7]);
    }
    stage_w(cow);
    __syncthreads();
    mm(cob);
    ln(g3, b3, false);

    // ---- phase 4: t2 = xs2@fw+fb ; res = xs3 = LN4(t2)+xs2
    __syncthreads();
    stage_x_res();
    stage_w(fw);
    __syncthreads();
    mm(fb);
    ln(g4, b4, false);

    // ---- phase 5: out = xs3 @ conv2^T + cb
    __syncthreads();
    stage_x_res();
    {
        const int o5 = t >> 2, c5 = (t & 3) * 16;
#pragma unroll
        for (int k = 0; k < 16; k++) wt[c5 + k][o5] = cw[o5 * 64 + c5 + k];
    }
    __syncthreads();
    mm(cb);
    float* op = out + (tok0 + r) * 64 + olo;
    *(float4*)op = make_float4(acc[0], acc[1], acc[2], acc[3]);
    *(float4*)(op + 4) = make_float4(acc[4], acc[5], acc[6], acc[7]);
}

// ---------------------------------------------------------------------------
extern "C" void kernel_launch(void* const* d_in, const int* in_sizes, int n_in,
                              void* d_out, int out_size, void* d_ws, size_t ws_size,
                              hipStream_t stream) {
    const float* x       = (const float*)d_in[0];
    const float* slots   = (const float*)d_in[1];
    const float* conv1_w = (const float*)d_in[2];
    const float* conv1_b = (const float*)d_in[3];
    const float* conv2_w = (const float*)d_in[4];
    const float* conv2_b = (const float*)d_in[5];
    const float* gn_g    = (const float*)d_in[6];
    const float* gn_b    = (const float*)d_in[7];
    const float* ln2_g   = (const float*)d_in[8];
    const float* ln2_b   = (const float*)d_in[9];
    const float* ln3_g   = (const float*)d_in[10];
    const float* ln3_b   = (const float*)d_in[11];
    const float* ln4_g   = (const float*)d_in[12];
    const float* ln4_b   = (const float*)d_in[13];
    const float* sa_qw   = (const float*)d_in[14];
    const float* sa_qb   = (const float*)d_in[15];
    const float* sa_kw   = (const float*)d_in[16];
    const float* sa_kb   = (const float*)d_in[17];
    const float* sa_vw   = (const float*)d_in[18];
    const float* sa_vb   = (const float*)d_in[19];
    const float* sa_ow   = (const float*)d_in[20];
    const float* sa_ob   = (const float*)d_in[21];
    const float* ca_qw   = (const float*)d_in[22];
    const float* ca_qb   = (const float*)d_in[23];
    const float* ca_kw   = (const float*)d_in[24];
    const float* ca_kb   = (const float*)d_in[25];
    const float* ca_vw   = (const float*)d_in[26];
    const float* ca_vb   = (const float*)d_in[27];
    const float* ca_ow   = (const float*)d_in[28];
    const float* ca_ob   = (const float*)d_in[29];
    const float* ff1_w   = (const float*)d_in[30];
    const float* ff1_b   = (const float*)d_in[31];

    float* ws = (float*)d_ws;
    const size_t NBUF = (size_t)NBATCH * LTOK * FD;   // 1,048,576 elements
    float* partS  = ws;                    // 1024
    float* partSS = ws + 1024;             // 1024
    float* A      = ws + 4096;             // xs0, 4 MB
    ushort* KF    = (ushort*)(A + NBUF);   // 2 MB (fragment layout)
    ushort* VF    = KF + NBUF;             // 2 MB (fragment layout)
    ushort* Qb    = VF + NBUF;             // 2 MB
    ushort* ZpAll = Qb + NBUF;             // 4 x 2 MB bf16 partials
    float* Ls     = (float*)(ZpAll + (size_t)KSPLIT * NBUF);  // 4 x 32768 floats

    gn_part_kernel<<<256, 256, 0, stream>>>(x, partS, partSS);
    gn_conv1_kernel<<<256, 256, 0, stream>>>(x, partS, partSS, gn_g, gn_b, conv1_w, conv1_b, A);
    qkv_kernel<<<dim3(256, 3), 256, 0, stream>>>(A, sa_qw, sa_qb, sa_kw, sa_kb, sa_vw, sa_vb, Qb, KF, VF);
    flash_mfma<<<dim3(32, 8, KSPLIT), 256, 0, stream>>>(Qb, KF, VF, ZpAll, Ls);
    tail_fused<<<512, 256, 0, stream>>>(ZpAll, Ls, A, slots,
                                        ca_kw, ca_kb, ca_vw, ca_vb,
                                        sa_ow, sa_ob, ln2_g, ln2_b,
                                        ca_qw, ca_qb, ca_ow, ca_ob, ln3_g, ln3_b,
                                        ff1_w, ff1_b, ln4_g, ln4_b,
                                        conv2_w, conv2_b, (float*)d_out);
}

// Round 13
// 87.381 us; speedup vs baseline: 1.1081x; 1.0152x over previous
//
#include <hip/hip_runtime.h>
#include <hip/hip_bf16.h>
#include <math.h>

#define NBATCH 4
#define LTOK   4096
#define FD     64
#define KSPLIT 8
#define MBLK   16    // 32-k fragment blocks per flash block = 4096/KSPLIT/32

typedef __attribute__((ext_vector_type(8))) short short8v;   // 8 bf16 = 4 VGPR
typedef __attribute__((ext_vector_type(4))) float f32x4;
typedef __attribute__((ext_vector_type(16))) float f32x16;

static __device__ inline uint32_t packbf2(float a, float b) {
    float2 f; f.x = a; f.y = b;
    __hip_bfloat162 h = __float22bfloat162_rn(f);
    uint32_t u; __builtin_memcpy(&u, &h, 4);
    return u;
}
static __device__ inline ushort packbf1(float a) {
    __hip_bfloat16 h = __float2bfloat16(a);
    ushort u; __builtin_memcpy(&u, &h, 2);
    return u;
}
static __device__ inline float gelu_exact(float y) {
    return 0.5f * y * (1.0f + erff(y * 0.70710678118654752f));
}

// ---------------------------------------------------------------------------
// K1: GroupNorm partial sums. 256 blocks (64 chunks per batch), coalesced.
__global__ void gn_part_kernel(const float* __restrict__ x,
                               float* __restrict__ partS, float* __restrict__ partSS) {
    const int b = blockIdx.x >> 6, c = blockIdx.x & 63;
    const int t = threadIdx.x, l = t & 63, wv = t >> 6;
    const float4* xb = (const float4*)(x + (size_t)b * 262144) + (size_t)c * 1024;
    float s = 0.f, ss = 0.f;
#pragma unroll
    for (int k = 0; k < 4; k++) {
        float4 v = xb[t + 256 * k];
        s += (v.x + v.y) + (v.z + v.w);
        ss += (v.x * v.x + v.y * v.y) + (v.z * v.z + v.w * v.w);
    }
#pragma unroll
    for (int o = 0; o < 4; o++) {
        const int off = (int[]){1, 2, 16, 32}[o];
        s += __shfl_xor(s, off, 64);
        ss += __shfl_xor(ss, off, 64);
    }
    __shared__ float ls_s[4][4], ls_ss[4][4];
    if ((l & 51) == 0) { ls_s[wv][(l >> 2) & 3] = s; ls_ss[wv][(l >> 2) & 3] = ss; }
    __syncthreads();
    if (t < 4) {
        float S = 0.f, SS = 0.f;
#pragma unroll
        for (int w2 = 0; w2 < 4; w2++) { S += ls_s[w2][t]; SS += ls_ss[w2][t]; }
        partS[b * 256 + t * 64 + c] = S;
        partSS[b * 256 + t * 64 + c] = SS;
    }
}

// ---------------------------------------------------------------------------
// K2: combine partials + GN-apply + conv1 + channels-first reshape.
__global__ void gn_conv1_kernel(const float* __restrict__ x,
                                const float* __restrict__ partS, const float* __restrict__ partSS,
                                const float* __restrict__ gg, const float* __restrict__ gb,
                                const float* __restrict__ w, const float* __restrict__ bias,
                                float* __restrict__ out) {
    const int b = blockIdx.x >> 6, i = blockIdx.x & 63;
    const int t = threadIdx.x;
    __shared__ float xn[64][65];
    __shared__ float wsm[64][64];   // [c][o]
    __shared__ float sm[4], sr[4];
    {
        float sv = partS[b * 256 + t];     // g = t>>6, chunk = t&63
        float ssv = partSS[b * 256 + t];
        for (int o = 32; o; o >>= 1) { sv += __shfl_xor(sv, o, 64); ssv += __shfl_xor(ssv, o, 64); }
        if ((t & 63) == 0) {
            float mean = sv * (1.f / 65536.f);
            float var = ssv * (1.f / 65536.f) - mean * mean;
            sm[t >> 6] = mean;
            sr[t >> 6] = rsqrtf(var + 1e-5f);
        }
    }
    __syncthreads();
    {
        const int j = t >> 2, c0 = (t & 3) * 16, g = c0 >> 4;
        const float mean = sm[g], rstd = sr[g];
        const float* src = x + (((size_t)b * 64 + i) * 64 + j) * 64 + c0;
#pragma unroll
        for (int k = 0; k < 4; k++) {
            float4 v = *(const float4*)(src + 4 * k);
            xn[j][c0 + 4 * k + 0] = (v.x - mean) * rstd * gg[c0 + 4 * k + 0] + gb[c0 + 4 * k + 0];
            xn[j][c0 + 4 * k + 1] = (v.y - mean) * rstd * gg[c0 + 4 * k + 1] + gb[c0 + 4 * k + 1];
            xn[j][c0 + 4 * k + 2] = (v.z - mean) * rstd * gg[c0 + 4 * k + 2] + gb[c0 + 4 * k + 2];
            xn[j][c0 + 4 * k + 3] = (v.w - mean) * rstd * gg[c0 + 4 * k + 3] + gb[c0 + 4 * k + 3];
        }
        const int o = t >> 2, cc0 = (t & 3) * 16;
#pragma unroll
        for (int k = 0; k < 16; k++) wsm[cc0 + k][o] = w[o * 64 + cc0 + k];
    }
    __syncthreads();
    const int jj = t & 63, olo = (t >> 6) * 16;
    float acc[16];
#pragma unroll
    for (int oi = 0; oi < 16; oi++) acc[oi] = bias[olo + oi];
    for (int c = 0; c < 64; c++) {
        float xv = xn[jj][c];
#pragma unroll
        for (int oi = 0; oi < 16; oi++) acc[oi] += xv * wsm[c][olo + oi];
    }
#pragma unroll
    for (int oi = 0; oi < 16; oi++)
        out[((size_t)b * LTOK + (size_t)(olo + oi) * 64 + i) * 64 + jj] = acc[oi];
}

// ---------------------------------------------------------------------------
// K3: Q/K/V projection, one phase per block (grid 256 x 3). R8-verified.
__global__ void qkv_kernel(const float* __restrict__ in,
                           const float* __restrict__ qw, const float* __restrict__ qb,
                           const float* __restrict__ kw, const float* __restrict__ kb,
                           const float* __restrict__ vw, const float* __restrict__ vb,
                           ushort* __restrict__ Qo, ushort* __restrict__ KF, ushort* __restrict__ VF) {
    __shared__ float xt[64][68];
    __shared__ float wt[64][64];
    __shared__ ushort vtr[64 * 72];
    const int t = threadIdx.x;
    const int ph = blockIdx.y;
    const size_t tok0 = (size_t)blockIdx.x * 64;
    const int b = blockIdx.x >> 6;
    const int tokb0 = (blockIdx.x & 63) * 64;
    const int r = t >> 2, cq = t & 3, olo = cq * 16;
    const float* W = (ph == 0) ? qw : (ph == 1) ? kw : vw;
    const float* Bb = (ph == 0) ? qb : (ph == 1) ? kb : vb;
    {
        const float4* src = (const float4*)(in + tok0 * 64) + (size_t)t * 4;
        float4* dst = (float4*)&xt[r][olo];
#pragma unroll
        for (int k = 0; k < 4; k++) dst[k] = src[k];
        const float4* ws2 = (const float4*)W + (size_t)t * 4;
        float4* wd = (float4*)wt + (size_t)t * 4;
#pragma unroll
        for (int k = 0; k < 4; k++) wd[k] = ws2[k];
    }
    __syncthreads();
    float acc[16];
#pragma unroll
    for (int k = 0; k < 4; k++) {
        float4 bv = *(const float4*)(Bb + olo + 4 * k);
        acc[4 * k] = bv.x; acc[4 * k + 1] = bv.y; acc[4 * k + 2] = bv.z; acc[4 * k + 3] = bv.w;
    }
    for (int f = 0; f < 64; f++) {
        float xv = xt[r][f];
#pragma unroll
        for (int oi = 0; oi < 16; oi++) acc[oi] += xv * wt[f][olo + oi];
    }
    if (ph == 0) {
        const float sc = 0.180336880111f;   // 0.125 * log2(e)
        uint32_t u[8];
#pragma unroll
        for (int i = 0; i < 8; i++) u[i] = packbf2(acc[2 * i] * sc, acc[2 * i + 1] * sc);
        ushort* op = Qo + (tok0 + r) * 64 + olo;
        *(uint4*)op = make_uint4(u[0], u[1], u[2], u[3]);
        *(uint4*)(op + 8) = make_uint4(u[4], u[5], u[6], u[7]);
    } else if (ph == 1) {
        uint32_t u[8];
#pragma unroll
        for (int i = 0; i < 8; i++) u[i] = packbf2(acc[2 * i], acc[2 * i + 1]);
        const int tokb = tokb0 + r;
        const int m = tokb >> 5, tq = tokb & 31;
        const int hh = cq >> 1, f = cq & 1;
        const int bhh = b * 2 + hh;
        ushort* p0 = KF + ((size_t)(bhh * 128 + m) * 2 + f) * 512;
        *(uint4*)(p0 + tq * 8)        = make_uint4(u[0], u[1], u[2], u[3]);   // sig=0
        *(uint4*)(p0 + (32 + tq) * 8) = make_uint4(u[4], u[5], u[6], u[7]);   // sig=1
    } else {
#pragma unroll
        for (int oi = 0; oi < 16; oi++) vtr[(olo + oi) * 72 + r] = packbf1(acc[oi]);
        __syncthreads();
        const int o = t >> 2, ch = t & 3;
        const int lq2 = o & 31, hh = o >> 5, bhh = b * 2 + hh;
        const int m = (tokb0 >> 5) + (ch >> 1), f = ch & 1;
        uint4 a0 = *(const uint4*)&vtr[o * 72 + ch * 16];
        uint4 a1 = *(const uint4*)&vtr[o * 72 + ch * 16 + 8];
        ushort* p0 = VF + ((size_t)(bhh * 128 + m) * 2 + f) * 512;
        *(uint4*)(p0 + lq2 * 8)        = a0;   // sig=0
        *(uint4*)(p0 + (32 + lq2) * 8) = a1;   // sig=1
    }
}

// ---------------------------------------------------------------------------
// K4: MFMA flash — no LDS/barriers, fragment loads from L2. 32 q per wave.
// Grid (32, 8, 8) = 2048 blocks. R10 structure + DUAL PV ACCUMULATORS
// (even/odd m) to halve the serial MFMA acc dependency chain.
__global__ __launch_bounds__(256, 4) void flash_mfma(const ushort* __restrict__ Q,
                                                     const ushort* __restrict__ KF,
                                                     const ushort* __restrict__ VF,
                                                     ushort* __restrict__ ZpAll,
                                                     float* __restrict__ Ls) {
    const int qt = blockIdx.x;            // 0..31 (128-q tiles)
    const int bh = blockIdx.y;            // 0..7
    const int ks = blockIdx.z;            // 0..7
    const int b = bh >> 1, h = bh & 1;
    const int t = threadIdx.x;
    const int w = t >> 6, l = t & 63, lq = l & 31, sig = l >> 5;

    const size_t base = (size_t)b * LTOK * 64 + h * 32;
    const int q0 = qt * 128 + w * 32;

    const ushort* qp = Q + base + (size_t)(q0 + lq) * 64 + 8 * sig;
    const short8v qf0 = *(const short8v*)(qp);
    const short8v qf1 = *(const short8v*)(qp + 16);

    const ushort* kfp = KF + ((size_t)(bh * 128 + ks * MBLK) * 2) * 512 + l * 8;
    const ushort* vfp = VF + ((size_t)(bh * 128 + ks * MBLK) * 2) * 512 + l * 8;

    f32x16 accE, accO;
#pragma unroll
    for (int i = 0; i < 16; i++) { accE[i] = 0.f; accO[i] = 0.f; }
    float lacc0 = 0.f, lacc1 = 0.f;

#pragma unroll 2
    for (int m = 0; m < MBLK; m++) {
        const short8v kf0 = *(const short8v*)kfp;
        const short8v kf1 = *(const short8v*)(kfp + 512);
        const short8v vf0 = *(const short8v*)vfp;
        const short8v vf1 = *(const short8v*)(vfp + 512);
        kfp += 1024; vfp += 1024;

        f32x16 st;
#pragma unroll
        for (int i = 0; i < 16; i++) st[i] = 0.f;
        st = __builtin_amdgcn_mfma_f32_32x32x16_bf16(kf0, qf0, st, 0, 0, 0);
        st = __builtin_amdgcn_mfma_f32_32x32x16_bf16(kf1, qf1, st, 0, 0, 0);

        uint32_t pk[8];
#pragma unroll
        for (int i = 0; i < 8; i++) {
            float p0 = __builtin_amdgcn_exp2f(st[2 * i]);
            float p1 = __builtin_amdgcn_exp2f(st[2 * i + 1]);
            if (i & 1) lacc1 += p0 + p1; else lacc0 += p0 + p1;
            pk[i] = packbf2(p0, p1);
        }
        uint32_t w0 = pk[0], w2 = pk[2], w1 = pk[1], w3 = pk[3];
        uint32_t x0 = pk[4], x2 = pk[6], x1 = pk[5], x3 = pk[7];
        asm volatile("v_permlane32_swap_b32 %0, %1" : "+v"(w0), "+v"(w2));
        asm volatile("v_permlane32_swap_b32 %0, %1" : "+v"(w1), "+v"(w3));
        asm volatile("v_permlane32_swap_b32 %0, %1" : "+v"(x0), "+v"(x2));
        asm volatile("v_permlane32_swap_b32 %0, %1" : "+v"(x1), "+v"(x3));
        uint4 A0 = make_uint4(w0, w1, w2, w3), A1 = make_uint4(x0, x1, x2, x3);
        short8v aP0, aP1;
        __builtin_memcpy(&aP0, &A0, 16);
        __builtin_memcpy(&aP1, &A1, 16);

        if (m & 1) {
            accO = __builtin_amdgcn_mfma_f32_32x32x16_bf16(aP0, vf0, accO, 0, 0, 0);
            accO = __builtin_amdgcn_mfma_f32_32x32x16_bf16(aP1, vf1, accO, 0, 0, 0);
        } else {
            accE = __builtin_amdgcn_mfma_f32_32x32x16_bf16(aP0, vf0, accE, 0, 0, 0);
            accE = __builtin_amdgcn_mfma_f32_32x32x16_bf16(aP1, vf1, accE, 0, 0, 0);
        }
    }

    ushort* Zo = ZpAll + (size_t)ks * (NBATCH * LTOK * FD);
#pragma unroll
    for (int r = 0; r < 16; r++) {
        const int qr = q0 + (r & 3) + 8 * (r >> 2) + 4 * sig;
        Zo[base + (size_t)qr * 64 + lq] = packbf1(accE[r] + accO[r]);
    }
    float lacc = lacc0 + lacc1;
    lacc += __shfl_xor(lacc, 32, 64);
    if (l < 32)
        Ls[ks * 32768 + bh * 4096 + q0 + lq] = lacc;
}

// ---------------------------------------------------------------------------
// K8: fused tail — Z-combine(8 bf16) + ow+LN2+GELU, ca_kv, ca_q, cross-attn,
// ca_ow+LN3, ff1+LN4, conv2. 512 blocks x 256 threads (R10-verified).
__global__ __launch_bounds__(256) void tail_fused(
    const ushort* __restrict__ ZpAll,
    const float* __restrict__ Ls, const float* __restrict__ xs0,
    const float* __restrict__ slots,
    const float* __restrict__ ckw, const float* __restrict__ ckb,
    const float* __restrict__ cvw, const float* __restrict__ cvb,
    const float* __restrict__ ow, const float* __restrict__ ob,
    const float* __restrict__ g2, const float* __restrict__ b2,
    const float* __restrict__ qw, const float* __restrict__ qb,
    const float* __restrict__ cow, const float* __restrict__ cob,
    const float* __restrict__ g3, const float* __restrict__ b3,
    const float* __restrict__ fw, const float* __restrict__ fb,
    const float* __restrict__ g4, const float* __restrict__ b4,
    const float* __restrict__ cw, const float* __restrict__ cb,
    float* __restrict__ out)
{
    const int t = threadIdx.x;
    const size_t tok0 = (size_t)blockIdx.x * 32;
    const int b = blockIdx.x >> 7;
    const int r = t >> 3, c = t & 7, olo = c * 8;
    __shared__ float xt[32][68];
    __shared__ float wt[64][64];
    __shared__ float kcs[512], vcs[512], sls[512];

    float acc[8], res[8];

    auto stage_w = [&](const float* W) {
#pragma unroll
        for (int k = 0; k < 4; k++)
            ((float4*)wt)[4 * t + k] = ((const float4*)W)[4 * t + k];
    };
    auto stage_x_res = [&]() {
        float4* xd = (float4*)&xt[r][olo];
        xd[0] = make_float4(res[0], res[1], res[2], res[3]);
        xd[1] = make_float4(res[4], res[5], res[6], res[7]);
    };
    auto load8 = [&](float* dst, const float* p) {
        float4 u0 = *(const float4*)(p + olo);
        float4 u1 = *(const float4*)(p + olo + 4);
        dst[0] = u0.x; dst[1] = u0.y; dst[2] = u0.z; dst[3] = u0.w;
        dst[4] = u1.x; dst[5] = u1.y; dst[6] = u1.z; dst[7] = u1.w;
    };
    auto mm = [&](const float* bias) {
        load8(acc, bias);
        for (int f = 0; f < 64; f++) {
            float xv = xt[r][f];
#pragma unroll
            for (int oi = 0; oi < 8; oi++) acc[oi] += xv * wt[f][olo + oi];
        }
    };
    auto ln = [&](const float* gv, const float* bv, bool dogelu) {
        float s1 = 0.f, s2 = 0.f;
#pragma unroll
        for (int oi = 0; oi < 8; oi++) { s1 += acc[oi]; s2 += acc[oi] * acc[oi]; }
#pragma unroll
        for (int o = 1; o <= 4; o <<= 1) {
            s1 += __shfl_xor(s1, o, 64);
            s2 += __shfl_xor(s2, o, 64);
        }
        float mean = s1 * (1.f / 64.f);
        float var = s2 * (1.f / 64.f) - mean * mean;
        float rstd = rsqrtf(var + 1e-5f);
        float gl[8], bl[8];
        load8(gl, gv); load8(bl, bv);
#pragma unroll
        for (int oi = 0; oi < 8; oi++) {
            float y = (acc[oi] - mean) * rstd * gl[oi] + bl[oi] + res[oi];
            res[oi] = dogelu ? gelu_exact(y) : y;
        }
    };

    // ---- phase 1: combine 8 bf16 flash partials, t0 = Z@ow+ob ; res = xs1
    {
        if (t < 128) ((float4*)sls)[t] = ((const float4*)(slots + (size_t)b * 512))[t];
        float zs[8];
#pragma unroll
        for (int j = 0; j < 8; j++) zs[j] = 0.f;
#pragma unroll
        for (int kb = 0; kb < KSPLIT; kb++) {
            const uint4 u = *(const uint4*)(ZpAll + (size_t)kb * (NBATCH * LTOK * FD)
                                            + tok0 * 64 + (size_t)t * 8);
            const uint32_t arr[4] = {u.x, u.y, u.z, u.w};
#pragma unroll
            for (int j = 0; j < 4; j++) {
                zs[2 * j]     += __uint_as_float(arr[j] << 16);
                zs[2 * j + 1] += __uint_as_float(arr[j] & 0xffff0000u);
            }
        }
        const int hh = olo >> 5;
        const int bh_ = b * 2 + hh;
        const int tokb = (blockIdx.x & 127) * 32 + r;
        float lt = 0.f;
#pragma unroll
        for (int kb = 0; kb < KSPLIT; kb++) lt += Ls[kb * 32768 + bh_ * 4096 + tokb];
        const float inv = 1.0f / lt;
        float4* xd = (float4*)&xt[r][olo];
        xd[0] = make_float4(zs[0] * inv, zs[1] * inv, zs[2] * inv, zs[3] * inv);
        xd[1] = make_float4(zs[4] * inv, zs[5] * inv, zs[6] * inv, zs[7] * inv);
        stage_w(ow);
        float4 r0 = *(const float4*)(xs0 + (tok0 + r) * 64 + olo);
        float4 r1 = *(const float4*)(xs0 + (tok0 + r) * 64 + olo + 4);
        res[0] = r0.x; res[1] = r0.y; res[2] = r0.z; res[3] = r0.w;
        res[4] = r1.x; res[5] = r1.y; res[6] = r1.z; res[7] = r1.w;
    }
    __syncthreads();
    // ---- cross-attn K/V from slots (redundant per block, cheap)
    for (int jo = t; jo < 512; jo += 256) {
        const int j = jo >> 6, o = jo & 63;
        float ak = ckb[o], av = cvb[o];
#pragma unroll 8
        for (int c2 = 0; c2 < 64; c2++) {
            float sv = sls[j * 64 + c2];
            ak += sv * ckw[c2 * 64 + o];
            av += sv * cvw[c2 * 64 + o];
        }
        kcs[jo] = ak; vcs[jo] = av;
    }
    mm(ob);
    ln(g2, b2, true);

    // ---- phase 2: qca = xs1@qw+qb ; acc = cross-attn(zca)
    __syncthreads();
    stage_x_res();
    stage_w(qw);
    __syncthreads();
    mm(qb);
    {
        float p[8];
        float mx = -3.0e38f;
#pragma unroll
        for (int j = 0; j < 8; j++) {
            float d = 0.f;
#pragma unroll
            for (int i2 = 0; i2 < 8; i2++) d += acc[i2] * kcs[j * 64 + olo + i2];
            d += __shfl_xor(d, 1, 64);
            d += __shfl_xor(d, 2, 64);
            d *= 0.125f;
            p[j] = d;
            mx = fmaxf(mx, d);
        }
        float es = 0.f;
#pragma unroll
        for (int j = 0; j < 8; j++) { p[j] = __expf(p[j] - mx); es += p[j]; }
        float inv = 1.f / es;
#pragma unroll
        for (int oi = 0; oi < 8; oi++) {
            float z = 0.f;
#pragma unroll
            for (int j = 0; j < 8; j++) z += p[j] * vcs[j * 64 + olo + oi];
            acc[oi] = z * inv;
        }
    }

    // ---- phase 3: t1 = zca@cow+cob ; res = xs2 = LN3(t1)+xs1
    __syncthreads();
    {
        float4* xd = (float4*)&xt[r][olo];
        xd[0] = make_float4(acc[0], acc[1], acc[2], acc[3]);
        xd[1] = make_float4(acc[4], acc[5], acc[6], acc[7]);
    }
    stage_w(cow);
    __syncthreads();
    mm(cob);
    ln(g3, b3, false);

    // ---- phase 4: t2 = xs2@fw+fb ; res = xs3 = LN4(t2)+xs2
    __syncthreads();
    stage_x_res();
    stage_w(fw);
    __syncthreads();
    mm(fb);
    ln(g4, b4, false);

    // ---- phase 5: out = xs3 @ conv2^T + cb
    __syncthreads();
    stage_x_res();
    {
        const int o5 = t >> 2, c5 = (t & 3) * 16;
#pragma unroll
        for (int k = 0; k < 16; k++) wt[c5 + k][o5] = cw[o5 * 64 + c5 + k];
    }
    __syncthreads();
    mm(cb);
    float* op = out + (tok0 + r) * 64 + olo;
    *(float4*)op = make_float4(acc[0], acc[1], acc[2], acc[3]);
    *(float4*)(op + 4) = make_float4(acc[4], acc[5], acc[6], acc[7]);
}

// ---------------------------------------------------------------------------
extern "C" void kernel_launch(void* const* d_in, const int* in_sizes, int n_in,
                              void* d_out, int out_size, void* d_ws, size_t ws_size,
                              hipStream_t stream) {
    const float* x       = (const float*)d_in[0];
    const float* slots   = (const float*)d_in[1];
    const float* conv1_w = (const float*)d_in[2];
    const float* conv1_b = (const float*)d_in[3];
    const float* conv2_w = (const float*)d_in[4];
    const float* conv2_b = (const float*)d_in[5];
    const float* gn_g    = (const float*)d_in[6];
    const float* gn_b    = (const float*)d_in[7];
    const float* ln2_g   = (const float*)d_in[8];
    const float* ln2_b   = (const float*)d_in[9];
    const float* ln3_g   = (const float*)d_in[10];
    const float* ln3_b   = (const float*)d_in[11];
    const float* ln4_g   = (const float*)d_in[12];
    const float* ln4_b   = (const float*)d_in[13];
    const float* sa_qw   = (const float*)d_in[14];
    const float* sa_qb   = (const float*)d_in[15];
    const float* sa_kw   = (const float*)d_in[16];
    const float* sa_kb   = (const float*)d_in[17];
    const float* sa_vw   = (const float*)d_in[18];
    const float* sa_vb   = (const float*)d_in[19];
    const float* sa_ow   = (const float*)d_in[20];
    const float* sa_ob   = (const float*)d_in[21];
    const float* ca_qw   = (const float*)d_in[22];
    const float* ca_qb   = (const float*)d_in[23];
    const float* ca_kw   = (const float*)d_in[24];
    const float* ca_kb   = (const float*)d_in[25];
    const float* ca_vw   = (const float*)d_in[26];
    const float* ca_vb   = (const float*)d_in[27];
    const float* ca_ow   = (const float*)d_in[28];
    const float* ca_ob   = (const float*)d_in[29];
    const float* ff1_w   = (const float*)d_in[30];
    const float* ff1_b   = (const float*)d_in[31];

    float* ws = (float*)d_ws;
    const size_t NBUF = (size_t)NBATCH * LTOK * FD;   // 1,048,576 elements
    float* partS  = ws;                    // 1024
    float* partSS = ws + 1024;             // 1024
    float* A      = ws + 4096;             // xs0, 4 MB
    ushort* KF    = (ushort*)(A + NBUF);   // 2 MB (fragment layout)
    ushort* VF    = KF + NBUF;             // 2 MB (fragment layout)
    ushort* Qb    = VF + NBUF;             // 2 MB
    ushort* ZpAll = Qb + NBUF;             // 8 x 2 MB bf16 partials
    float* Ls     = (float*)(ZpAll + (size_t)KSPLIT * NBUF);  // 8 x 32768 floats

    gn_part_kernel<<<256, 256, 0, stream>>>(x, partS, partSS);
    gn_conv1_kernel<<<256, 256, 0, stream>>>(x, partS, partSS, gn_g, gn_b, conv1_w, conv1_b, A);
    qkv_kernel<<<dim3(256, 3), 256, 0, stream>>>(A, sa_qw, sa_qb, sa_kw, sa_kb, sa_vw, sa_vb, Qb, KF, VF);
    flash_mfma<<<dim3(32, 8, KSPLIT), 256, 0, stream>>>(Qb, KF, VF, ZpAll, Ls);
    tail_fused<<<512, 256, 0, stream>>>(ZpAll, Ls, A, slots,
                                        ca_kw, ca_kb, ca_vw, ca_vb,
                                        sa_ow, sa_ob, ln2_g, ln2_b,
                                        ca_qw, ca_qb, ca_ow, ca_ob, ln3_g, ln3_b,
                                        ff1_w, ff1_b, ln4_g, ln4_b,
                                        conv2_w, conv2_b, (float*)d_out);
}

// Round 14
// 86.910 us; speedup vs baseline: 1.1141x; 1.0054x over previous
//
#include <hip/hip_runtime.h>
#include <hip/hip_bf16.h>
#include <math.h>

#define NBATCH 4
#define LTOK   4096
#define FD     64
#define KSPLIT 8
#define MBLK   16    // 32-k fragment blocks per flash block = 4096/KSPLIT/32

typedef __attribute__((ext_vector_type(8))) short short8v;   // 8 bf16 = 4 VGPR
typedef __attribute__((ext_vector_type(4))) float f32x4;
typedef __attribute__((ext_vector_type(16))) float f32x16;

static __device__ inline uint32_t packbf2(float a, float b) {
    float2 f; f.x = a; f.y = b;
    __hip_bfloat162 h = __float22bfloat162_rn(f);
    uint32_t u; __builtin_memcpy(&u, &h, 4);
    return u;
}
static __device__ inline ushort packbf1(float a) {
    __hip_bfloat16 h = __float2bfloat16(a);
    ushort u; __builtin_memcpy(&u, &h, 2);
    return u;
}
static __device__ inline float gelu_exact(float y) {
    return 0.5f * y * (1.0f + erff(y * 0.70710678118654752f));
}

// ---------------------------------------------------------------------------
// K1: GroupNorm partial sums. 256 blocks (64 chunks per batch), coalesced.
__global__ void gn_part_kernel(const float* __restrict__ x,
                               float* __restrict__ partS, float* __restrict__ partSS) {
    const int b = blockIdx.x >> 6, c = blockIdx.x & 63;
    const int t = threadIdx.x, l = t & 63, wv = t >> 6;
    const float4* xb = (const float4*)(x + (size_t)b * 262144) + (size_t)c * 1024;
    float s = 0.f, ss = 0.f;
#pragma unroll
    for (int k = 0; k < 4; k++) {
        float4 v = xb[t + 256 * k];
        s += (v.x + v.y) + (v.z + v.w);
        ss += (v.x * v.x + v.y * v.y) + (v.z * v.z + v.w * v.w);
    }
#pragma unroll
    for (int o = 0; o < 4; o++) {
        const int off = (int[]){1, 2, 16, 32}[o];
        s += __shfl_xor(s, off, 64);
        ss += __shfl_xor(ss, off, 64);
    }
    __shared__ float ls_s[4][4], ls_ss[4][4];
    if ((l & 51) == 0) { ls_s[wv][(l >> 2) & 3] = s; ls_ss[wv][(l >> 2) & 3] = ss; }
    __syncthreads();
    if (t < 4) {
        float S = 0.f, SS = 0.f;
#pragma unroll
        for (int w2 = 0; w2 < 4; w2++) { S += ls_s[w2][t]; SS += ls_ss[w2][t]; }
        partS[b * 256 + t * 64 + c] = S;
        partSS[b * 256 + t * 64 + c] = SS;
    }
}

// ---------------------------------------------------------------------------
// K2: combine partials + GN-apply + conv1 + channels-first reshape.
__global__ void gn_conv1_kernel(const float* __restrict__ x,
                                const float* __restrict__ partS, const float* __restrict__ partSS,
                                const float* __restrict__ gg, const float* __restrict__ gb,
                                const float* __restrict__ w, const float* __restrict__ bias,
                                float* __restrict__ out) {
    const int b = blockIdx.x >> 6, i = blockIdx.x & 63;
    const int t = threadIdx.x;
    __shared__ float xn[64][65];
    __shared__ float wsm[64][64];   // [c][o]
    __shared__ float sm[4], sr[4];
    {
        float sv = partS[b * 256 + t];     // g = t>>6, chunk = t&63
        float ssv = partSS[b * 256 + t];
        for (int o = 32; o; o >>= 1) { sv += __shfl_xor(sv, o, 64); ssv += __shfl_xor(ssv, o, 64); }
        if ((t & 63) == 0) {
            float mean = sv * (1.f / 65536.f);
            float var = ssv * (1.f / 65536.f) - mean * mean;
            sm[t >> 6] = mean;
            sr[t >> 6] = rsqrtf(var + 1e-5f);
        }
    }
    __syncthreads();
    {
        const int j = t >> 2, c0 = (t & 3) * 16, g = c0 >> 4;
        const float mean = sm[g], rstd = sr[g];
        const float* src = x + (((size_t)b * 64 + i) * 64 + j) * 64 + c0;
#pragma unroll
        for (int k = 0; k < 4; k++) {
            float4 v = *(const float4*)(src + 4 * k);
            xn[j][c0 + 4 * k + 0] = (v.x - mean) * rstd * gg[c0 + 4 * k + 0] + gb[c0 + 4 * k + 0];
            xn[j][c0 + 4 * k + 1] = (v.y - mean) * rstd * gg[c0 + 4 * k + 1] + gb[c0 + 4 * k + 1];
            xn[j][c0 + 4 * k + 2] = (v.z - mean) * rstd * gg[c0 + 4 * k + 2] + gb[c0 + 4 * k + 2];
            xn[j][c0 + 4 * k + 3] = (v.w - mean) * rstd * gg[c0 + 4 * k + 3] + gb[c0 + 4 * k + 3];
        }
        const int o = t >> 2, cc0 = (t & 3) * 16;
#pragma unroll
        for (int k = 0; k < 16; k++) wsm[cc0 + k][o] = w[o * 64 + cc0 + k];
    }
    __syncthreads();
    const int jj = t & 63, olo = (t >> 6) * 16;
    float acc[16];
#pragma unroll
    for (int oi = 0; oi < 16; oi++) acc[oi] = bias[olo + oi];
    for (int c = 0; c < 64; c++) {
        float xv = xn[jj][c];
#pragma unroll
        for (int oi = 0; oi < 16; oi++) acc[oi] += xv * wsm[c][olo + oi];
    }
#pragma unroll
    for (int oi = 0; oi < 16; oi++)
        out[((size_t)b * LTOK + (size_t)(olo + oi) * 64 + i) * 64 + jj] = acc[oi];
}

// ---------------------------------------------------------------------------
// K3: Q/K/V projection, one phase per block (grid 256 x 3). R8-verified.
__global__ void qkv_kernel(const float* __restrict__ in,
                           const float* __restrict__ qw, const float* __restrict__ qb,
                           const float* __restrict__ kw, const float* __restrict__ kb,
                           const float* __restrict__ vw, const float* __restrict__ vb,
                           ushort* __restrict__ Qo, ushort* __restrict__ KF, ushort* __restrict__ VF) {
    __shared__ float xt[64][68];
    __shared__ float wt[64][64];
    __shared__ ushort vtr[64 * 72];
    const int t = threadIdx.x;
    const int ph = blockIdx.y;
    const size_t tok0 = (size_t)blockIdx.x * 64;
    const int b = blockIdx.x >> 6;
    const int tokb0 = (blockIdx.x & 63) * 64;
    const int r = t >> 2, cq = t & 3, olo = cq * 16;
    const float* W = (ph == 0) ? qw : (ph == 1) ? kw : vw;
    const float* Bb = (ph == 0) ? qb : (ph == 1) ? kb : vb;
    {
        const float4* src = (const float4*)(in + tok0 * 64) + (size_t)t * 4;
        float4* dst = (float4*)&xt[r][olo];
#pragma unroll
        for (int k = 0; k < 4; k++) dst[k] = src[k];
        const float4* ws2 = (const float4*)W + (size_t)t * 4;
        float4* wd = (float4*)wt + (size_t)t * 4;
#pragma unroll
        for (int k = 0; k < 4; k++) wd[k] = ws2[k];
    }
    __syncthreads();
    float acc[16];
#pragma unroll
    for (int k = 0; k < 4; k++) {
        float4 bv = *(const float4*)(Bb + olo + 4 * k);
        acc[4 * k] = bv.x; acc[4 * k + 1] = bv.y; acc[4 * k + 2] = bv.z; acc[4 * k + 3] = bv.w;
    }
    for (int f = 0; f < 64; f++) {
        float xv = xt[r][f];
#pragma unroll
        for (int oi = 0; oi < 16; oi++) acc[oi] += xv * wt[f][olo + oi];
    }
    if (ph == 0) {
        const float sc = 0.180336880111f;   // 0.125 * log2(e)
        uint32_t u[8];
#pragma unroll
        for (int i = 0; i < 8; i++) u[i] = packbf2(acc[2 * i] * sc, acc[2 * i + 1] * sc);
        ushort* op = Qo + (tok0 + r) * 64 + olo;
        *(uint4*)op = make_uint4(u[0], u[1], u[2], u[3]);
        *(uint4*)(op + 8) = make_uint4(u[4], u[5], u[6], u[7]);
    } else if (ph == 1) {
        uint32_t u[8];
#pragma unroll
        for (int i = 0; i < 8; i++) u[i] = packbf2(acc[2 * i], acc[2 * i + 1]);
        const int tokb = tokb0 + r;
        const int m = tokb >> 5, tq = tokb & 31;
        const int hh = cq >> 1, f = cq & 1;
        const int bhh = b * 2 + hh;
        ushort* p0 = KF + ((size_t)(bhh * 128 + m) * 2 + f) * 512;
        *(uint4*)(p0 + tq * 8)        = make_uint4(u[0], u[1], u[2], u[3]);   // sig=0
        *(uint4*)(p0 + (32 + tq) * 8) = make_uint4(u[4], u[5], u[6], u[7]);   // sig=1
    } else {
#pragma unroll
        for (int oi = 0; oi < 16; oi++) vtr[(olo + oi) * 72 + r] = packbf1(acc[oi]);
        __syncthreads();
        const int o = t >> 2, ch = t & 3;
        const int lq2 = o & 31, hh = o >> 5, bhh = b * 2 + hh;
        const int m = (tokb0 >> 5) + (ch >> 1), f = ch & 1;
        uint4 a0 = *(const uint4*)&vtr[o * 72 + ch * 16];
        uint4 a1 = *(const uint4*)&vtr[o * 72 + ch * 16 + 8];
        ushort* p0 = VF + ((size_t)(bhh * 128 + m) * 2 + f) * 512;
        *(uint4*)(p0 + lq2 * 8)        = a0;   // sig=0
        *(uint4*)(p0 + (32 + lq2) * 8) = a1;   // sig=1
    }
}

// ---------------------------------------------------------------------------
// K4: MFMA flash — no LDS/barriers, fragment loads from L2. 32 q per wave.
// Grid (32, 8, 8) = 2048 blocks. R10-verified best configuration.
__global__ __launch_bounds__(256, 5) void flash_mfma(const ushort* __restrict__ Q,
                                                     const ushort* __restrict__ KF,
                                                     const ushort* __restrict__ VF,
                                                     ushort* __restrict__ ZpAll,
                                                     float* __restrict__ Ls) {
    const int qt = blockIdx.x;            // 0..31 (128-q tiles)
    const int bh = blockIdx.y;            // 0..7
    const int ks = blockIdx.z;            // 0..7
    const int b = bh >> 1, h = bh & 1;
    const int t = threadIdx.x;
    const int w = t >> 6, l = t & 63, lq = l & 31, sig = l >> 5;

    const size_t base = (size_t)b * LTOK * 64 + h * 32;
    const int q0 = qt * 128 + w * 32;

    const ushort* qp = Q + base + (size_t)(q0 + lq) * 64 + 8 * sig;
    const short8v qf0 = *(const short8v*)(qp);
    const short8v qf1 = *(const short8v*)(qp + 16);

    const ushort* kfp = KF + ((size_t)(bh * 128 + ks * MBLK) * 2) * 512 + l * 8;
    const ushort* vfp = VF + ((size_t)(bh * 128 + ks * MBLK) * 2) * 512 + l * 8;

    f32x16 acc;
#pragma unroll
    for (int i = 0; i < 16; i++) acc[i] = 0.f;
    float lacc0 = 0.f, lacc1 = 0.f;

#pragma unroll 2
    for (int m = 0; m < MBLK; m++) {
        const short8v kf0 = *(const short8v*)kfp;
        const short8v kf1 = *(const short8v*)(kfp + 512);
        const short8v vf0 = *(const short8v*)vfp;
        const short8v vf1 = *(const short8v*)(vfp + 512);
        kfp += 1024; vfp += 1024;

        f32x16 st;
#pragma unroll
        for (int i = 0; i < 16; i++) st[i] = 0.f;
        st = __builtin_amdgcn_mfma_f32_32x32x16_bf16(kf0, qf0, st, 0, 0, 0);
        st = __builtin_amdgcn_mfma_f32_32x32x16_bf16(kf1, qf1, st, 0, 0, 0);

        uint32_t pk[8];
#pragma unroll
        for (int i = 0; i < 8; i++) {
            float p0 = __builtin_amdgcn_exp2f(st[2 * i]);
            float p1 = __builtin_amdgcn_exp2f(st[2 * i + 1]);
            if (i & 1) lacc1 += p0 + p1; else lacc0 += p0 + p1;
            pk[i] = packbf2(p0, p1);
        }
        uint32_t w0 = pk[0], w2 = pk[2], w1 = pk[1], w3 = pk[3];
        uint32_t x0 = pk[4], x2 = pk[6], x1 = pk[5], x3 = pk[7];
        asm volatile("v_permlane32_swap_b32 %0, %1" : "+v"(w0), "+v"(w2));
        asm volatile("v_permlane32_swap_b32 %0, %1" : "+v"(w1), "+v"(w3));
        asm volatile("v_permlane32_swap_b32 %0, %1" : "+v"(x0), "+v"(x2));
        asm volatile("v_permlane32_swap_b32 %0, %1" : "+v"(x1), "+v"(x3));
        uint4 A0 = make_uint4(w0, w1, w2, w3), A1 = make_uint4(x0, x1, x2, x3);
        short8v aP0, aP1;
        __builtin_memcpy(&aP0, &A0, 16);
        __builtin_memcpy(&aP1, &A1, 16);

        acc = __builtin_amdgcn_mfma_f32_32x32x16_bf16(aP0, vf0, acc, 0, 0, 0);
        acc = __builtin_amdgcn_mfma_f32_32x32x16_bf16(aP1, vf1, acc, 0, 0, 0);
    }

    ushort* Zo = ZpAll + (size_t)ks * (NBATCH * LTOK * FD);
#pragma unroll
    for (int r = 0; r < 16; r++) {
        const int qr = q0 + (r & 3) + 8 * (r >> 2) + 4 * sig;
        Zo[base + (size_t)qr * 64 + lq] = packbf1(acc[r]);
    }
    float lacc = lacc0 + lacc1;
    lacc += __shfl_xor(lacc, 32, 64);
    if (l < 32)
        Ls[ks * 32768 + bh * 4096 + q0 + lq] = lacc;
}

// ---------------------------------------------------------------------------
// K8: fused tail — Z-combine(8 bf16) + ow+LN2+GELU, ca_kv, ca_q, cross-attn,
// ca_ow+LN3, ff1+LN4, conv2. 512 blocks x 256 threads (R10-verified).
__global__ __launch_bounds__(256) void tail_fused(
    const ushort* __restrict__ ZpAll,
    const float* __restrict__ Ls, const float* __restrict__ xs0,
    const float* __restrict__ slots,
    const float* __restrict__ ckw, const float* __restrict__ ckb,
    const float* __restrict__ cvw, const float* __restrict__ cvb,
    const float* __restrict__ ow, const float* __restrict__ ob,
    const float* __restrict__ g2, const float* __restrict__ b2,
    const float* __restrict__ qw, const float* __restrict__ qb,
    const float* __restrict__ cow, const float* __restrict__ cob,
    const float* __restrict__ g3, const float* __restrict__ b3,
    const float* __restrict__ fw, const float* __restrict__ fb,
    const float* __restrict__ g4, const float* __restrict__ b4,
    const float* __restrict__ cw, const float* __restrict__ cb,
    float* __restrict__ out)
{
    const int t = threadIdx.x;
    const size_t tok0 = (size_t)blockIdx.x * 32;
    const int b = blockIdx.x >> 7;
    const int r = t >> 3, c = t & 7, olo = c * 8;
    __shared__ float xt[32][68];
    __shared__ float wt[64][64];
    __shared__ float kcs[512], vcs[512], sls[512];

    float acc[8], res[8];

    auto stage_w = [&](const float* W) {
#pragma unroll
        for (int k = 0; k < 4; k++)
            ((float4*)wt)[4 * t + k] = ((const float4*)W)[4 * t + k];
    };
    auto stage_x_res = [&]() {
        float4* xd = (float4*)&xt[r][olo];
        xd[0] = make_float4(res[0], res[1], res[2], res[3]);
        xd[1] = make_float4(res[4], res[5], res[6], res[7]);
    };
    auto load8 = [&](float* dst, const float* p) {
        float4 u0 = *(const float4*)(p + olo);
        float4 u1 = *(const float4*)(p + olo + 4);
        dst[0] = u0.x; dst[1] = u0.y; dst[2] = u0.z; dst[3] = u0.w;
        dst[4] = u1.x; dst[5] = u1.y; dst[6] = u1.z; dst[7] = u1.w;
    };
    auto mm = [&](const float* bias) {
        load8(acc, bias);
        for (int f = 0; f < 64; f++) {
            float xv = xt[r][f];
#pragma unroll
            for (int oi = 0; oi < 8; oi++) acc[oi] += xv * wt[f][olo + oi];
        }
    };
    auto ln = [&](const float* gv, const float* bv, bool dogelu) {
        float s1 = 0.f, s2 = 0.f;
#pragma unroll
        for (int oi = 0; oi < 8; oi++) { s1 += acc[oi]; s2 += acc[oi] * acc[oi]; }
#pragma unroll
        for (int o = 1; o <= 4; o <<= 1) {
            s1 += __shfl_xor(s1, o, 64);
            s2 += __shfl_xor(s2, o, 64);
        }
        float mean = s1 * (1.f / 64.f);
        float var = s2 * (1.f / 64.f) - mean * mean;
        float rstd = rsqrtf(var + 1e-5f);
        float gl[8], bl[8];
        load8(gl, gv); load8(bl, bv);
#pragma unroll
        for (int oi = 0; oi < 8; oi++) {
            float y = (acc[oi] - mean) * rstd * gl[oi] + bl[oi] + res[oi];
            res[oi] = dogelu ? gelu_exact(y) : y;
        }
    };

    // ---- phase 1: combine 8 bf16 flash partials, t0 = Z@ow+ob ; res = xs1
    {
        if (t < 128) ((float4*)sls)[t] = ((const float4*)(slots + (size_t)b * 512))[t];
        float zs[8];
#pragma unroll
        for (int j = 0; j < 8; j++) zs[j] = 0.f;
#pragma unroll
        for (int kb = 0; kb < KSPLIT; kb++) {
            const uint4 u = *(const uint4*)(ZpAll + (size_t)kb * (NBATCH * LTOK * FD)
                                            + tok0 * 64 + (size_t)t * 8);
            const uint32_t arr[4] = {u.x, u.y, u.z, u.w};
#pragma unroll
            for (int j = 0; j < 4; j++) {
                zs[2 * j]     += __uint_as_float(arr[j] << 16);
                zs[2 * j + 1] += __uint_as_float(arr[j] & 0xffff0000u);
            }
        }
        const int hh = olo >> 5;
        const int bh_ = b * 2 + hh;
        const int tokb = (blockIdx.x & 127) * 32 + r;
        float lt = 0.f;
#pragma unroll
        for (int kb = 0; kb < KSPLIT; kb++) lt += Ls[kb * 32768 + bh_ * 4096 + tokb];
        const float inv = 1.0f / lt;
        float4* xd = (float4*)&xt[r][olo];
        xd[0] = make_float4(zs[0] * inv, zs[1] * inv, zs[2] * inv, zs[3] * inv);
        xd[1] = make_float4(zs[4] * inv, zs[5] * inv, zs[6] * inv, zs[7] * inv);
        stage_w(ow);
        float4 r0 = *(const float4*)(xs0 + (tok0 + r) * 64 + olo);
        float4 r1 = *(const float4*)(xs0 + (tok0 + r) * 64 + olo + 4);
        res[0] = r0.x; res[1] = r0.y; res[2] = r0.z; res[3] = r0.w;
        res[4] = r1.x; res[5] = r1.y; res[6] = r1.z; res[7] = r1.w;
    }
    __syncthreads();
    // ---- cross-attn K/V from slots (redundant per block, cheap)
    for (int jo = t; jo < 512; jo += 256) {
        const int j = jo >> 6, o = jo & 63;
        float ak = ckb[o], av = cvb[o];
#pragma unroll 8
        for (int c2 = 0; c2 < 64; c2++) {
            float sv = sls[j * 64 + c2];
            ak += sv * ckw[c2 * 64 + o];
            av += sv * cvw[c2 * 64 + o];
        }
        kcs[jo] = ak; vcs[jo] = av;
    }
    mm(ob);
    ln(g2, b2, true);

    // ---- phase 2: qca = xs1@qw+qb ; acc = cross-attn(zca)
    __syncthreads();
    stage_x_res();
    stage_w(qw);
    __syncthreads();
    mm(qb);
    {
        float p[8];
        float mx = -3.0e38f;
#pragma unroll
        for (int j = 0; j < 8; j++) {
            float d = 0.f;
#pragma unroll
            for (int i2 = 0; i2 < 8; i2++) d += acc[i2] * kcs[j * 64 + olo + i2];
            d += __shfl_xor(d, 1, 64);
            d += __shfl_xor(d, 2, 64);
            d *= 0.125f;
            p[j] = d;
            mx = fmaxf(mx, d);
        }
        float es = 0.f;
#pragma unroll
        for (int j = 0; j < 8; j++) { p[j] = __expf(p[j] - mx); es += p[j]; }
        float inv = 1.f / es;
#pragma unroll
        for (int oi = 0; oi < 8; oi++) {
            float z = 0.f;
#pragma unroll
            for (int j = 0; j < 8; j++) z += p[j] * vcs[j * 64 + olo + oi];
            acc[oi] = z * inv;
        }
    }

    // ---- phase 3: t1 = zca@cow+cob ; res = xs2 = LN3(t1)+xs1
    __syncthreads();
    {
        float4* xd = (float4*)&xt[r][olo];
        xd[0] = make_float4(acc[0], acc[1], acc[2], acc[3]);
        xd[1] = make_float4(acc[4], acc[5], acc[6], acc[7]);
    }
    stage_w(cow);
    __syncthreads();
    mm(cob);
    ln(g3, b3, false);

    // ---- phase 4: t2 = xs2@fw+fb ; res = xs3 = LN4(t2)+xs2
    __syncthreads();
    stage_x_res();
    stage_w(fw);
    __syncthreads();
    mm(fb);
    ln(g4, b4, false);

    // ---- phase 5: out = xs3 @ conv2^T + cb
    __syncthreads();
    stage_x_res();
    {
        const int o5 = t >> 2, c5 = (t & 3) * 16;
#pragma unroll
        for (int k = 0; k < 16; k++) wt[c5 + k][o5] = cw[o5 * 64 + c5 + k];
    }
    __syncthreads();
    mm(cb);
    float* op = out + (tok0 + r) * 64 + olo;
    *(float4*)op = make_float4(acc[0], acc[1], acc[2], acc[3]);
    *(float4*)(op + 4) = make_float4(acc[4], acc[5], acc[6], acc[7]);
}

// ---------------------------------------------------------------------------
extern "C" void kernel_launch(void* const* d_in, const int* in_sizes, int n_in,
                              void* d_out, int out_size, void* d_ws, size_t ws_size,
                              hipStream_t stream) {
    const float* x       = (const float*)d_in[0];
    const float* slots   = (const float*)d_in[1];
    const float* conv1_w = (const float*)d_in[2];
    const float* conv1_b = (const float*)d_in[3];
    const float* conv2_w = (const float*)d_in[4];
    const float* conv2_b = (const float*)d_in[5];
    const float* gn_g    = (const float*)d_in[6];
    const float* gn_b    = (const float*)d_in[7];
    const float* ln2_g   = (const float*)d_in[8];
    const float* ln2_b   = (const float*)d_in[9];
    const float* ln3_g   = (const float*)d_in[10];
    const float* ln3_b   = (const float*)d_in[11];
    const float* ln4_g   = (const float*)d_in[12];
    const float* ln4_b   = (const float*)d_in[13];
    const float* sa_qw   = (const float*)d_in[14];
    const float* sa_qb   = (const float*)d_in[15];
    const float* sa_kw   = (const float*)d_in[16];
    const float* sa_kb   = (const float*)d_in[17];
    const float* sa_vw   = (const float*)d_in[18];
    const float* sa_vb   = (const float*)d_in[19];
    const float* sa_ow   = (const float*)d_in[20];
    const float* sa_ob   = (const float*)d_in[21];
    const float* ca_qw   = (const float*)d_in[22];
    const float* ca_qb   = (const float*)d_in[23];
    const float* ca_kw   = (const float*)d_in[24];
    const float* ca_kb   = (const float*)d_in[25];
    const float* ca_vw   = (const float*)d_in[26];
    const float* ca_vb   = (const float*)d_in[27];
    const float* ca_ow   = (const float*)d_in[28];
    const float* ca_ob   = (const float*)d_in[29];
    const float* ff1_w   = (const float*)d_in[30];
    const float* ff1_b   = (const float*)d_in[31];

    float* ws = (float*)d_ws;
    const size_t NBUF = (size_t)NBATCH * LTOK * FD;   // 1,048,576 elements
    float* partS  = ws;                    // 1024
    float* partSS = ws + 1024;             // 1024
    float* A      = ws + 4096;             // xs0, 4 MB
    ushort* KF    = (ushort*)(A + NBUF);   // 2 MB (fragment layout)
    ushort* VF    = KF + NBUF;             // 2 MB (fragment layout)
    ushort* Qb    = VF + NBUF;             // 2 MB
    ushort* ZpAll = Qb + NBUF;             // 8 x 2 MB bf16 partials
    float* Ls     = (float*)(ZpAll + (size_t)KSPLIT * NBUF);  // 8 x 32768 floats

    gn_part_kernel<<<256, 256, 0, stream>>>(x, partS, partSS);
    gn_conv1_kernel<<<256, 256, 0, stream>>>(x, partS, partSS, gn_g, gn_b, conv1_w, conv1_b, A);
    qkv_kernel<<<dim3(256, 3), 256, 0, stream>>>(A, sa_qw, sa_qb, sa_kw, sa_kb, sa_vw, sa_vb, Qb, KF, VF);
    flash_mfma<<<dim3(32, 8, KSPLIT), 256, 0, stream>>>(Qb, KF, VF, ZpAll, Ls);
    tail_fused<<<512, 256, 0, stream>>>(ZpAll, Ls, A, slots,
                                        ca_kw, ca_kb, ca_vw, ca_vb,
                                        sa_ow, sa_ob, ln2_g, ln2_b,
                                        ca_qw, ca_qb, ca_ow, ca_ob, ln3_g, ln3_b,
                                        ff1_w, ff1_b, ln4_g, ln4_b,
                                        conv2_w, conv2_b, (float*)d_out);
}